// Round 16
// baseline (918.246 us; speedup 1.0000x reference)
//
#include <hip/hip_runtime.h>

#define B 128
#define C 32
#define HH 16
#define V 4096
#define MARGIN 2e-4f

typedef __attribute__((ext_vector_type(8))) short bf16x8;
typedef __attribute__((ext_vector_type(4))) float f32x4;

// ---------------- helpers ----------------

__device__ __forceinline__ float cubicw(float t) {
    float at = fabsf(t);
    float at2 = at * at, at3 = at2 * at;
    if (at <= 1.f) return 1.25f * at3 - 2.25f * at2 + 1.f;
    if (at < 2.f)  return -0.75f * at3 + 3.75f * at2 - 6.f * at + 3.f;
    return 0.f;
}

__device__ __forceinline__ unsigned short f2bf_rne(float f) {
    unsigned int u = __float_as_uint(f);
    unsigned int r = (u + 0x7fffu + ((u >> 16) & 1u)) >> 16;
    return (unsigned short)r;
}
__device__ __forceinline__ float bf2f(unsigned short h) {
    return __uint_as_float(((unsigned int)h) << 16);
}

// ---------------- kernels ----------------

// setup: f_rest=feat, f_hat=0, c2 (fp64+fp32), stage-0 z, codebook bf16 hi/lo frag tables
// frag layout: elem i -> ii=i&7, nn=(i>>3)&15, kb=(i>>7)&3, T=i>>9; code v=T*16+nn, k=kb*8+ii
// => wave reads tile T as bf16x8[ T*64 + lane ]  (fully coalesced 16B/lane)
__global__ void setup_kernel(const float* __restrict__ feat, float* __restrict__ f_rest,
                             float* __restrict__ f_hat, const float* __restrict__ cb,
                             double* __restrict__ c2d, float* __restrict__ c2f,
                             float* __restrict__ z0, unsigned short* __restrict__ cbh,
                             unsigned short* __restrict__ cbl) {
    int i = blockIdx.x * 256 + threadIdx.x;
    if (i < B * C * HH * HH) { f_rest[i] = feat[i]; f_hat[i] = 0.f; }
    if (i < V) {
        const float* p = cb + i * C;
        double s = 0.0;
        #pragma unroll
        for (int j = 0; j < C; ++j) { double d = (double)p[j]; s = fma(d, d, s); }
        c2d[i] = s;
        c2f[i] = (float)s;
    }
    if (i < B * C) {
        const float* p = feat + i * (HH * HH);
        float s = 0.f;
        for (int px = 0; px < HH * HH; ++px) s += p[px];
        z0[i] = s * (1.f / 256.f);
    }
    if (i < V * C) {
        int ii = i & 7, nn = (i >> 3) & 15, kb = (i >> 7) & 3, T = i >> 9;
        float val = cb[(T * 16 + nn) * C + kb * 8 + ii];
        unsigned short h = f2bf_rne(val);
        cbh[i] = h;
        cbl[i] = f2bf_rne(val - bf2f(h));
    }
}

// ---- MFMA top-2 scan: wave = 32 tokens x (V/nseg) codes; 16x16x32 bf16, 4 hi/lo passes ----
__global__ __launch_bounds__(256, 4) void scan_mfma_kernel(
    const float* __restrict__ z, const unsigned short* __restrict__ cbh,
    const unsigned short* __restrict__ cbl, const float* __restrict__ c2f,
    float* __restrict__ pb1, float* __restrict__ pb2, int* __restrict__ pi1,
    int npx, int nseg, int ngrp)
{
    int tid = threadIdx.x;
    int wave = tid >> 6, lane = tid & 63;
    int job = blockIdx.x * 4 + wave;
    int seg = job / ngrp, tokgrp = job - seg * ngrp;
    int cps = V / nseg;
    int total = B * npx;
    int tn = lane & 15, kb = lane >> 4;

    // A fragments: token = tok0 + g*16 + tn (row), k = kb*8 + i
    bf16x8 ah[2], al[2];
    #pragma unroll
    for (int g = 0; g < 2; ++g) {
        int tok = tokgrp * 32 + g * 16 + tn;
        int bq = tok / npx, n = tok - bq * npx;
        #pragma unroll
        for (int i = 0; i < 8; ++i) {
            float v = z[(bq * C + kb * 8 + i) * npx + n];
            unsigned short h = f2bf_rne(v);
            ah[g][i] = (short)h;
            al[g][i] = (short)f2bf_rne(v - bf2f(h));
        }
    }

    const bf16x8* ph = reinterpret_cast<const bf16x8*>(cbh);
    const bf16x8* pl = reinterpret_cast<const bf16x8*>(cbl);

    float b1[8], b2[8]; int i1[8];
    #pragma unroll
    for (int s = 0; s < 8; ++s) { b1[s] = 3e38f; b2[s] = 3e38f; i1[s] = 0; }

    int T0 = seg * (cps >> 4), nT = cps >> 4;
    #pragma unroll 2
    for (int t = 0; t < nT; ++t) {
        int T = T0 + t;
        bf16x8 bh = ph[(size_t)T * 64 + lane];
        bf16x8 bl = pl[(size_t)T * 64 + lane];
        float c2v = c2f[T * 16 + tn];

        f32x4 a0 = {0.f, 0.f, 0.f, 0.f}, a1 = {0.f, 0.f, 0.f, 0.f};
        a0 = __builtin_amdgcn_mfma_f32_16x16x32_bf16(ah[0], bh, a0, 0, 0, 0);
        a0 = __builtin_amdgcn_mfma_f32_16x16x32_bf16(al[0], bh, a0, 0, 0, 0);
        a0 = __builtin_amdgcn_mfma_f32_16x16x32_bf16(ah[0], bl, a0, 0, 0, 0);
        a0 = __builtin_amdgcn_mfma_f32_16x16x32_bf16(al[0], bl, a0, 0, 0, 0);
        a1 = __builtin_amdgcn_mfma_f32_16x16x32_bf16(ah[1], bh, a1, 0, 0, 0);
        a1 = __builtin_amdgcn_mfma_f32_16x16x32_bf16(al[1], bh, a1, 0, 0, 0);
        a1 = __builtin_amdgcn_mfma_f32_16x16x32_bf16(ah[1], bl, a1, 0, 0, 0);
        a1 = __builtin_amdgcn_mfma_f32_16x16x32_bf16(al[1], bl, a1, 0, 0, 0);

        int code = T * 16 + tn;   // lane's code column; ascending t -> strict < keeps lowest idx
        #pragma unroll
        for (int r = 0; r < 4; ++r) {
            float s0 = fmaf(-2.f, a0[r], c2v);
            if (s0 < b1[r]) { b2[r] = b1[r]; b1[r] = s0; i1[r] = code; }
            else if (s0 < b2[r]) { b2[r] = s0; }
            float s1 = fmaf(-2.f, a1[r], c2v);
            if (s1 < b1[4 + r]) { b2[4 + r] = b1[4 + r]; b1[4 + r] = s1; i1[4 + r] = code; }
            else if (s1 < b2[4 + r]) { b2[4 + r] = s1; }
        }
    }

    // merge across the 16 code-column lanes per token (D row = kb*4+r, token_local = g*16+kb*4+r)
    __shared__ float smb1[4 * 32 * 16];
    __shared__ float smb2[4 * 32 * 16];
    __shared__ int   smi1[4 * 32 * 16];
    #pragma unroll
    for (int g = 0; g < 2; ++g)
        #pragma unroll
        for (int r = 0; r < 4; ++r) {
            int tokl = g * 16 + kb * 4 + r;
            int base = wave * 512 + tokl * 16 + tn;
            smb1[base] = b1[g * 4 + r];
            smb2[base] = b2[g * 4 + r];
            smi1[base] = i1[g * 4 + r];
        }
    __syncthreads();
    if (tid < 128) {
        int w = tid >> 5, tl = tid & 31;
        int jobw = blockIdx.x * 4 + w;
        int segw = jobw / ngrp, tgw = jobw - segw * ngrp;
        float gb1 = 3e38f, gb2 = 3e38f; int gi1 = 0;
        #pragma unroll
        for (int i = 0; i < 16; ++i) {
            float v1 = smb1[w * 512 + tl * 16 + i];
            int   ix = smi1[w * 512 + tl * 16 + i];
            if (v1 < gb1 || (v1 == gb1 && ix < gi1)) { gb2 = gb1; gb1 = v1; gi1 = ix; }
            else if (v1 < gb2) { gb2 = v1; }
            float v2 = smb2[w * 512 + tl * 16 + i];
            if (v2 < gb2) gb2 = v2;
        }
        int tok = tgw * 32 + tl;
        pb1[(size_t)segw * total + tok] = gb1;
        pb2[(size_t)segw * total + tok] = gb2;
        pi1[(size_t)segw * total + tok] = gi1;
    }
}

// fused tail (R15, unchanged): combine + fp64 recheck + gather + separable bicubic
//                              + conv + blend/update + context pool + next-z pool
__global__ __launch_bounds__(256) void stage_tail_kernel(
    const float* __restrict__ pb1, const float* __restrict__ pb2,
    const int* __restrict__ pi1, const float* __restrict__ z,
    const float* __restrict__ cb, const double* __restrict__ c2d,
    const float* __restrict__ w, const float* __restrict__ bias,
    float* __restrict__ f_hat, float* __restrict__ f_rest,
    float* __restrict__ out, float* __restrict__ znext,
    int pn, int off, int pn2, int nseg)
{
    int bb = blockIdx.x >> 2;
    int og = (blockIdx.x & 3) * 8;
    int tid = threadIdx.x;
    int npx = pn * pn;
    int total = B * npx;

    __shared__ float A_s[32][260];
    __shared__ float B_s[32][260];
    __shared__ int idx_s[256];
    __shared__ int flist[256];
    __shared__ int fcnt;
    __shared__ double zsd[C];
    __shared__ double sred[256];
    __shared__ int sidx[256];
    __shared__ float wtab[16][4];
    __shared__ int   itab[16][4];
    float (*fh_s)[260] = &B_s[0];
    float (*fr_s)[260] = &B_s[8];

    float pf[8], pr[8];
    #pragma unroll
    for (int o = 0; o < 8; ++o) {
        int gi = (bb * 32 + og + o) * 256 + tid;
        pf[o] = f_hat[gi]; pr[o] = f_rest[gi];
    }

    if (tid < 16) {
        float scale = (float)pn * (1.f / 16.f);
        float src = (tid + 0.5f) * scale - 0.5f;
        int fi = (int)floorf(src);
        float t = src - (float)fi;
        #pragma unroll
        for (int k = 0; k < 4; ++k) {
            wtab[tid][k] = cubicw((float)(k - 1) - t);
            itab[tid][k] = min(max(fi + k - 1, 0), pn - 1);
        }
    }
    if (tid == 0) fcnt = 0;
    __syncthreads();

    if (tid < npx) {
        int tok = bb * npx + tid;
        float gb1 = 3e38f, gb2 = 3e38f; int gi1 = 0;
        for (int s = 0; s < nseg; ++s) {
            float v1 = pb1[(size_t)s * total + tok];
            int   ix = pi1[(size_t)s * total + tok];
            if (v1 < gb1 || (v1 == gb1 && ix < gi1)) { gb2 = gb1; gb1 = v1; gi1 = ix; }
            else if (v1 < gb2) { gb2 = v1; }
            float v2 = pb2[(size_t)s * total + tok];
            if (v2 < gb2) gb2 = v2;
        }
        idx_s[tid] = gi1;
        if (gb2 - gb1 < MARGIN) { int slot = atomicAdd(&fcnt, 1); flist[slot] = tid; }
    }
    __syncthreads();

    int nf = fcnt;
    for (int f = 0; f < nf; ++f) {
        int n = flist[f];
        if (tid < C) zsd[tid] = (double)z[(bb * C + tid) * npx + n];
        __syncthreads();
        double best = 1e300; int bi = 0x7fffffff;
        for (int k = 0; k < V / 256; ++k) {
            int v = tid + k * 256;
            const float4* cp = reinterpret_cast<const float4*>(cb + (size_t)v * C);
            double acc = 0.0;
            #pragma unroll
            for (int qq = 0; qq < 8; ++qq) {
                float4 fv = cp[qq];
                acc = fma((double)fv.x, zsd[4 * qq + 0], acc);
                acc = fma((double)fv.y, zsd[4 * qq + 1], acc);
                acc = fma((double)fv.z, zsd[4 * qq + 2], acc);
                acc = fma((double)fv.w, zsd[4 * qq + 3], acc);
            }
            double s = fma(-2.0, acc, c2d[v]);
            if (s < best || (s == best && v < bi)) { best = s; bi = v; }
        }
        sred[tid] = best; sidx[tid] = bi;
        __syncthreads();
        for (int st = 128; st > 0; st >>= 1) {
            if (tid < st) {
                double o = sred[tid + st]; int oi = sidx[tid + st];
                double me = sred[tid];     int mi = sidx[tid];
                if (o < me || (o == me && oi < mi)) { sred[tid] = o; sidx[tid] = oi; }
            }
            __syncthreads();
        }
        if (tid == 0) idx_s[n] = sidx[0];
        __syncthreads();
    }
    __syncthreads();

    for (int e = tid; e < 32 * npx; e += 256) {
        int c = e & 31, n = e >> 5;
        A_s[c][n] = cb[idx_s[n] * 32 + c];
    }
    __syncthreads();

    for (int e = tid; e < 32 * 16 * pn; e += 256) {
        int wx = e % pn; int rest = e / pn;
        int p = rest & 15, c = rest >> 4;
        float s = 0.f;
        #pragma unroll
        for (int k = 0; k < 4; ++k)
            s = fmaf(wtab[p][k], A_s[c][itab[p][k] * pn + wx], s);
        B_s[c][p * pn + wx] = s;
    }
    __syncthreads();

    #pragma unroll
    for (int it = 0; it < 32; ++it) {
        int e = tid + it * 256;
        int q = e & 15, p = (e >> 4) & 15, c = e >> 8;
        float s = 0.f;
        #pragma unroll
        for (int k = 0; k < 4; ++k)
            s = fmaf(wtab[q][k], B_s[c][p * pn + itab[q][k]], s);
        A_s[c][e & 255] = s;
    }
    __syncthreads();

    int p = tid >> 4, q = tid & 15;
    float acc[8];
    #pragma unroll
    for (int o = 0; o < 8; ++o) acc[o] = bias[og + o];
    for (int i = 0; i < 32; ++i) {
        float v[9];
        #pragma unroll
        for (int dy = 0; dy < 3; ++dy)
            #pragma unroll
            for (int dx = 0; dx < 3; ++dx) {
                int pp = p + dy - 1, qq = q + dx - 1;
                bool in = (pp >= 0) & (pp < 16) & (qq >= 0) & (qq < 16);
                v[dy * 3 + dx] = in ? A_s[i][pp * 16 + qq] : 0.f;
            }
        #pragma unroll
        for (int o = 0; o < 8; ++o) {
            const float* wp_ = w + ((og + o) * 32 + i) * 9;
            #pragma unroll
            for (int k = 0; k < 9; ++k) acc[o] = fmaf(wp_[k], v[k], acc[o]);
        }
    }
    float hv[8];
    #pragma unroll
    for (int o = 0; o < 8; ++o) hv[o] = A_s[og + o][tid];
    __syncthreads();

    #pragma unroll
    for (int o = 0; o < 8; ++o) {
        int gi = (bb * 32 + og + o) * 256 + tid;
        float blend = 0.5f * hv[o] + 0.5f * acc[o];
        float nf2 = pf[o] + blend;
        float nr2 = pr[o] - blend;
        f_hat[gi] = nf2; f_rest[gi] = nr2;
        fh_s[o][tid] = nf2; fr_s[o][tid] = nr2;
    }
    __syncthreads();

    for (int e = tid; e < 8 * npx; e += 256) {
        int o = e & 7, n = e >> 3;
        int y = n / pn, x = n - y * pn;
        int sh = (y * HH) / pn, eh = ((y + 1) * HH + pn - 1) / pn;
        int sw = (x * HH) / pn, ew = ((x + 1) * HH + pn - 1) / pn;
        float s = 0.f;
        for (int yy = sh; yy < eh; ++yy)
            for (int xx = sw; xx < ew; ++xx) s += fh_s[o][yy * 16 + xx];
        out[((bb * 680) + off + n) * 32 + og + o] = s * (1.f / (float)((eh - sh) * (ew - sw)));
    }

    if (pn2 > 0) {
        int npx2 = pn2 * pn2;
        for (int e = tid; e < 8 * npx2; e += 256) {
            int o = e / npx2, n = e - o * npx2;
            int y = n / pn2, x = n - y * pn2;
            int sh = (y * HH) / pn2, eh = ((y + 1) * HH + pn2 - 1) / pn2;
            int sw = (x * HH) / pn2, ew = ((x + 1) * HH + pn2 - 1) / pn2;
            float s = 0.f;
            for (int yy = sh; yy < eh; ++yy)
                for (int xx = sw; xx < ew; ++xx) s += fr_s[o][yy * 16 + xx];
            znext[(bb * 32 + og + o) * npx2 + n] = s * (1.f / (float)((eh - sh) * (ew - sw)));
        }
    }
}

// ---------------- launch ----------------

extern "C" void kernel_launch(void* const* d_in, const int* in_sizes, int n_in,
                              void* d_out, int out_size, void* d_ws, size_t ws_size,
                              hipStream_t stream) {
    const float* feat = (const float*)d_in[0];
    const float* cb   = (const float*)d_in[1];
    const float* phiw = (const float*)d_in[2];
    const float* phib = (const float*)d_in[3];
    float* out = (float*)d_out;
    float* wsf = (float*)d_ws;

    const int NE = B * C * HH * HH; // 1048576
    float* f_rest = wsf;
    float* f_hat  = wsf + NE;
    float* zA     = wsf + 2 * NE;
    float* zB     = wsf + 3 * NE;
    char*  tl     = (char*)(wsf + 4 * NE);
    double* c2d  = (double*)tl;                             // 32 KB
    float*  c2f  = (float*)(tl + (32 << 10));               // 16 KB
    float*  pb1  = (float*)(tl + (48 << 10));               // 1 MB each
    float*  pb2  = (float*)(tl + (48 << 10) + (1 << 20));
    int*    pi1  = (int*)  (tl + (48 << 10) + (2 << 20));
    unsigned short* cbh = (unsigned short*)(tl + (48 << 10) + (3 << 20));        // 256 KB
    unsigned short* cbl = (unsigned short*)(tl + (48 << 10) + (3 << 20) + (512 << 10));

    static const int PN_[10]   = {1, 2, 3, 4, 5, 6, 8, 10, 13, 16};
    static const int PI_[10]   = {0, 0, 1, 1, 1, 2, 2, 2, 3, 3};
    static const int OFF_[10]  = {0, 1, 5, 14, 30, 55, 91, 155, 255, 424};
    static const int NSEG_[10] = {32, 32, 32, 16, 16, 16, 8, 8, 4, 4};

    setup_kernel<<<dim3((NE + 255) / 256), dim3(256), 0, stream>>>(
        feat, f_rest, f_hat, cb, c2d, c2f, zA, cbh, cbl);

    for (int si = 0; si < 10; ++si) {
        int pn = PN_[si], npx = pn * pn;
        int tokens = B * npx;            // divisible by 32 at every stage
        int nseg = NSEG_[si];
        int ngrp = tokens / 32;
        int njobs = ngrp * nseg;         // divisible by 4 (nseg multiple of 4)
        float* zin  = (si & 1) ? zB : zA;
        float* zout = (si & 1) ? zA : zB;

        scan_mfma_kernel<<<dim3(njobs / 4), dim3(256), 0, stream>>>(
            zin, cbh, cbl, c2f, pb1, pb2, pi1, npx, nseg, ngrp);

        int pn2 = (si < 9) ? PN_[si + 1] : 0;
        stage_tail_kernel<<<dim3(B * 4), dim3(256), 0, stream>>>(
            pb1, pb2, pi1, zin, cb, c2d,
            phiw + PI_[si] * C * C * 9, phib + PI_[si] * C,
            f_hat, f_rest, out, zout, pn, OFF_[si], pn2, nseg);
    }
}

// Round 17
// 915.897 us; speedup vs baseline: 1.0026x; 1.0026x over previous
//
#include <hip/hip_runtime.h>

#define B 128
#define C 32
#define HH 16
#define V 4096
#define MARGIN 2e-4f

typedef __attribute__((ext_vector_type(8))) short bf16x8;
typedef __attribute__((ext_vector_type(4))) float f32x4;

// ---------------- helpers ----------------

__device__ __forceinline__ float cubicw(float t) {
    float at = fabsf(t);
    float at2 = at * at, at3 = at2 * at;
    if (at <= 1.f) return 1.25f * at3 - 2.25f * at2 + 1.f;
    if (at < 2.f)  return -0.75f * at3 + 3.75f * at2 - 6.f * at + 3.f;
    return 0.f;
}

__device__ __forceinline__ unsigned short f2bf_rne(float f) {
    unsigned int u = __float_as_uint(f);
    unsigned int r = (u + 0x7fffu + ((u >> 16) & 1u)) >> 16;
    return (unsigned short)r;
}
__device__ __forceinline__ float bf2f(unsigned short h) {
    return __uint_as_float(((unsigned int)h) << 16);
}

// ---------------- kernels ----------------

// setup: f_rest=feat, f_hat=0, c2 (fp64+fp32), stage-0 z, codebook bf16 hi/lo frag tables
// frag layout: elem i -> ii=i&7, nn=(i>>3)&15, kb=(i>>7)&3, T=i>>9; code v=T*16+nn, k=kb*8+ii
__global__ void setup_kernel(const float* __restrict__ feat, float* __restrict__ f_rest,
                             float* __restrict__ f_hat, const float* __restrict__ cb,
                             double* __restrict__ c2d, float* __restrict__ c2f,
                             float* __restrict__ z0, unsigned short* __restrict__ cbh,
                             unsigned short* __restrict__ cbl) {
    int i = blockIdx.x * 256 + threadIdx.x;
    if (i < B * C * HH * HH) { f_rest[i] = feat[i]; f_hat[i] = 0.f; }
    if (i < V) {
        const float* p = cb + i * C;
        double s = 0.0;
        #pragma unroll
        for (int j = 0; j < C; ++j) { double d = (double)p[j]; s = fma(d, d, s); }
        c2d[i] = s;
        c2f[i] = (float)s;
    }
    if (i < B * C) {
        const float* p = feat + i * (HH * HH);
        float s = 0.f;
        for (int px = 0; px < HH * HH; ++px) s += p[px];
        z0[i] = s * (1.f / 256.f);
    }
    if (i < V * C) {
        int ii = i & 7, nn = (i >> 3) & 15, kb = (i >> 7) & 3, T = i >> 9;
        float val = cb[(T * 16 + nn) * C + kb * 8 + ii];
        unsigned short h = f2bf_rne(val);
        cbh[i] = h;
        cbl[i] = f2bf_rne(val - bf2f(h));
    }
}

// ---- MFMA top-2 scan v2: wave = 32 tokens; A-fragments routed through LDS so the
// compiler cannot rematerialize them (R16: VGPR=48 + 600 VALU/tile = z reload+cvt
// per tile). Loop reads frags via ds_read_b128; reduction state stays in VGPRs. ----
__global__ __launch_bounds__(256, 4) void scan_mfma_kernel(
    const float* __restrict__ z, const unsigned short* __restrict__ cbh,
    const unsigned short* __restrict__ cbl, const float* __restrict__ c2f,
    float* __restrict__ pb1, float* __restrict__ pb2, int* __restrict__ pi1,
    int npx, int nseg, int ngrp)
{
    int tid = threadIdx.x;
    int wave = tid >> 6, lane = tid & 63;
    int job = blockIdx.x * 4 + wave;
    int seg = job / ngrp, tokgrp = job - seg * ngrp;
    int cps = V / nseg;
    int total = B * npx;
    int tn = lane & 15, kb = lane >> 4;

    // union: frag store during loop (16 KB), merge arrays after (26.1 KB)
    __shared__ alignas(16) char ldsu[26112];
    short* ldsA = (short*)ldsu;                 // [4][64][32]
    float* smb1 = (float*)ldsu;                 // [4][32*17]
    float* smb2 = (float*)(ldsu + 8704);
    int*   smi1 = (int*)(ldsu + 17408);

    // build this lane's 4 fragments (g0 hi, g0 lo, g1 hi, g1 lo) into LDS
    {
        short* slot = ldsA + (wave * 64 + lane) * 32;
        #pragma unroll
        for (int g = 0; g < 2; ++g) {
            int tok = tokgrp * 32 + g * 16 + tn;
            int bq = tok / npx, n = tok - bq * npx;
            #pragma unroll
            for (int i = 0; i < 8; ++i) {
                float v = z[(bq * C + kb * 8 + i) * npx + n];
                unsigned short h = f2bf_rne(v);
                slot[g * 16 + i]     = (short)h;
                slot[g * 16 + 8 + i] = (short)f2bf_rne(v - bf2f(h));
            }
        }
    }
    __syncthreads();

    const bf16x8* fr = reinterpret_cast<const bf16x8*>(ldsA + (wave * 64 + lane) * 32);
    bf16x8 a0h = fr[0], a0l = fr[1], a1h = fr[2], a1l = fr[3];

    const bf16x8* ph = reinterpret_cast<const bf16x8*>(cbh);
    const bf16x8* pl = reinterpret_cast<const bf16x8*>(cbl);

    float b1[8], b2[8]; int i1[8];
    #pragma unroll
    for (int s = 0; s < 8; ++s) { b1[s] = 3e38f; b2[s] = 3e38f; i1[s] = 0; }

    int T0 = seg * (cps >> 4), nT = cps >> 4;
    #pragma unroll 2
    for (int t = 0; t < nT; ++t) {
        int T = T0 + t;
        bf16x8 bh = ph[(size_t)T * 64 + lane];
        bf16x8 bl = pl[(size_t)T * 64 + lane];
        float c2v = c2f[T * 16 + tn];

        f32x4 a0 = {0.f, 0.f, 0.f, 0.f}, a1 = {0.f, 0.f, 0.f, 0.f};
        a0 = __builtin_amdgcn_mfma_f32_16x16x32_bf16(a0h, bh, a0, 0, 0, 0);
        a0 = __builtin_amdgcn_mfma_f32_16x16x32_bf16(a0l, bh, a0, 0, 0, 0);
        a0 = __builtin_amdgcn_mfma_f32_16x16x32_bf16(a0h, bl, a0, 0, 0, 0);
        a0 = __builtin_amdgcn_mfma_f32_16x16x32_bf16(a0l, bl, a0, 0, 0, 0);
        a1 = __builtin_amdgcn_mfma_f32_16x16x32_bf16(a1h, bh, a1, 0, 0, 0);
        a1 = __builtin_amdgcn_mfma_f32_16x16x32_bf16(a1l, bh, a1, 0, 0, 0);
        a1 = __builtin_amdgcn_mfma_f32_16x16x32_bf16(a1h, bl, a1, 0, 0, 0);
        a1 = __builtin_amdgcn_mfma_f32_16x16x32_bf16(a1l, bl, a1, 0, 0, 0);

        int code = T * 16 + tn;   // ascending with t -> strict < keeps lowest idx
        #pragma unroll
        for (int r = 0; r < 4; ++r) {
            float s0 = fmaf(-2.f, a0[r], c2v);
            if (s0 < b1[r]) { b2[r] = b1[r]; b1[r] = s0; i1[r] = code; }
            else if (s0 < b2[r]) { b2[r] = s0; }
            float s1 = fmaf(-2.f, a1[r], c2v);
            if (s1 < b1[4 + r]) { b2[4 + r] = b1[4 + r]; b1[4 + r] = s1; i1[4 + r] = code; }
            else if (s1 < b2[4 + r]) { b2[4 + r] = s1; }
        }
    }

    __syncthreads();   // frag region dead -> merge overlay (stride 17: conflict-free)
    #pragma unroll
    for (int g = 0; g < 2; ++g)
        #pragma unroll
        for (int r = 0; r < 4; ++r) {
            int tokl = g * 16 + kb * 4 + r;
            int base = wave * 544 + tokl * 17 + tn;
            smb1[base] = b1[g * 4 + r];
            smb2[base] = b2[g * 4 + r];
            smi1[base] = i1[g * 4 + r];
        }
    __syncthreads();
    if (tid < 128) {
        int w = tid >> 5, tl = tid & 31;
        int jobw = blockIdx.x * 4 + w;
        int segw = jobw / ngrp, tgw = jobw - segw * ngrp;
        float gb1 = 3e38f, gb2 = 3e38f; int gi1 = 0;
        #pragma unroll
        for (int i = 0; i < 16; ++i) {
            float v1 = smb1[w * 544 + tl * 17 + i];
            int   ix = smi1[w * 544 + tl * 17 + i];
            if (v1 < gb1 || (v1 == gb1 && ix < gi1)) { gb2 = gb1; gb1 = v1; gi1 = ix; }
            else if (v1 < gb2) { gb2 = v1; }
            float v2 = smb2[w * 544 + tl * 17 + i];
            if (v2 < gb2) gb2 = v2;
        }
        int tok = tgw * 32 + tl;
        pb1[(size_t)segw * total + tok] = gb1;
        pb2[(size_t)segw * total + tok] = gb2;
        pi1[(size_t)segw * total + tok] = gi1;
    }
}

// fused tail (R15, unchanged): combine + fp64 recheck + gather + separable bicubic
//                              + conv + blend/update + context pool + next-z pool
__global__ __launch_bounds__(256) void stage_tail_kernel(
    const float* __restrict__ pb1, const float* __restrict__ pb2,
    const int* __restrict__ pi1, const float* __restrict__ z,
    const float* __restrict__ cb, const double* __restrict__ c2d,
    const float* __restrict__ w, const float* __restrict__ bias,
    float* __restrict__ f_hat, float* __restrict__ f_rest,
    float* __restrict__ out, float* __restrict__ znext,
    int pn, int off, int pn2, int nseg)
{
    int bb = blockIdx.x >> 2;
    int og = (blockIdx.x & 3) * 8;
    int tid = threadIdx.x;
    int npx = pn * pn;
    int total = B * npx;

    __shared__ float A_s[32][260];
    __shared__ float B_s[32][260];
    __shared__ int idx_s[256];
    __shared__ int flist[256];
    __shared__ int fcnt;
    __shared__ double zsd[C];
    __shared__ double sred[256];
    __shared__ int sidx[256];
    __shared__ float wtab[16][4];
    __shared__ int   itab[16][4];
    float (*fh_s)[260] = &B_s[0];
    float (*fr_s)[260] = &B_s[8];

    float pf[8], pr[8];
    #pragma unroll
    for (int o = 0; o < 8; ++o) {
        int gi = (bb * 32 + og + o) * 256 + tid;
        pf[o] = f_hat[gi]; pr[o] = f_rest[gi];
    }

    if (tid < 16) {
        float scale = (float)pn * (1.f / 16.f);
        float src = (tid + 0.5f) * scale - 0.5f;
        int fi = (int)floorf(src);
        float t = src - (float)fi;
        #pragma unroll
        for (int k = 0; k < 4; ++k) {
            wtab[tid][k] = cubicw((float)(k - 1) - t);
            itab[tid][k] = min(max(fi + k - 1, 0), pn - 1);
        }
    }
    if (tid == 0) fcnt = 0;
    __syncthreads();

    if (tid < npx) {
        int tok = bb * npx + tid;
        float gb1 = 3e38f, gb2 = 3e38f; int gi1 = 0;
        for (int s = 0; s < nseg; ++s) {
            float v1 = pb1[(size_t)s * total + tok];
            int   ix = pi1[(size_t)s * total + tok];
            if (v1 < gb1 || (v1 == gb1 && ix < gi1)) { gb2 = gb1; gb1 = v1; gi1 = ix; }
            else if (v1 < gb2) { gb2 = v1; }
            float v2 = pb2[(size_t)s * total + tok];
            if (v2 < gb2) gb2 = v2;
        }
        idx_s[tid] = gi1;
        if (gb2 - gb1 < MARGIN) { int slot = atomicAdd(&fcnt, 1); flist[slot] = tid; }
    }
    __syncthreads();

    int nf = fcnt;
    for (int f = 0; f < nf; ++f) {
        int n = flist[f];
        if (tid < C) zsd[tid] = (double)z[(bb * C + tid) * npx + n];
        __syncthreads();
        double best = 1e300; int bi = 0x7fffffff;
        for (int k = 0; k < V / 256; ++k) {
            int v = tid + k * 256;
            const float4* cp = reinterpret_cast<const float4*>(cb + (size_t)v * C);
            double acc = 0.0;
            #pragma unroll
            for (int qq = 0; qq < 8; ++qq) {
                float4 fv = cp[qq];
                acc = fma((double)fv.x, zsd[4 * qq + 0], acc);
                acc = fma((double)fv.y, zsd[4 * qq + 1], acc);
                acc = fma((double)fv.z, zsd[4 * qq + 2], acc);
                acc = fma((double)fv.w, zsd[4 * qq + 3], acc);
            }
            double s = fma(-2.0, acc, c2d[v]);
            if (s < best || (s == best && v < bi)) { best = s; bi = v; }
        }
        sred[tid] = best; sidx[tid] = bi;
        __syncthreads();
        for (int st = 128; st > 0; st >>= 1) {
            if (tid < st) {
                double o = sred[tid + st]; int oi = sidx[tid + st];
                double me = sred[tid];     int mi = sidx[tid];
                if (o < me || (o == me && oi < mi)) { sred[tid] = o; sidx[tid] = oi; }
            }
            __syncthreads();
        }
        if (tid == 0) idx_s[n] = sidx[0];
        __syncthreads();
    }
    __syncthreads();

    for (int e = tid; e < 32 * npx; e += 256) {
        int c = e & 31, n = e >> 5;
        A_s[c][n] = cb[idx_s[n] * 32 + c];
    }
    __syncthreads();

    for (int e = tid; e < 32 * 16 * pn; e += 256) {
        int wx = e % pn; int rest = e / pn;
        int p = rest & 15, c = rest >> 4;
        float s = 0.f;
        #pragma unroll
        for (int k = 0; k < 4; ++k)
            s = fmaf(wtab[p][k], A_s[c][itab[p][k] * pn + wx], s);
        B_s[c][p * pn + wx] = s;
    }
    __syncthreads();

    #pragma unroll
    for (int it = 0; it < 32; ++it) {
        int e = tid + it * 256;
        int q = e & 15, p = (e >> 4) & 15, c = e >> 8;
        float s = 0.f;
        #pragma unroll
        for (int k = 0; k < 4; ++k)
            s = fmaf(wtab[q][k], B_s[c][p * pn + itab[q][k]], s);
        A_s[c][e & 255] = s;
    }
    __syncthreads();

    int p = tid >> 4, q = tid & 15;
    float acc[8];
    #pragma unroll
    for (int o = 0; o < 8; ++o) acc[o] = bias[og + o];
    for (int i = 0; i < 32; ++i) {
        float v[9];
        #pragma unroll
        for (int dy = 0; dy < 3; ++dy)
            #pragma unroll
            for (int dx = 0; dx < 3; ++dx) {
                int pp = p + dy - 1, qq = q + dx - 1;
                bool in = (pp >= 0) & (pp < 16) & (qq >= 0) & (qq < 16);
                v[dy * 3 + dx] = in ? A_s[i][pp * 16 + qq] : 0.f;
            }
        #pragma unroll
        for (int o = 0; o < 8; ++o) {
            const float* wp_ = w + ((og + o) * 32 + i) * 9;
            #pragma unroll
            for (int k = 0; k < 9; ++k) acc[o] = fmaf(wp_[k], v[k], acc[o]);
        }
    }
    float hv[8];
    #pragma unroll
    for (int o = 0; o < 8; ++o) hv[o] = A_s[og + o][tid];
    __syncthreads();

    #pragma unroll
    for (int o = 0; o < 8; ++o) {
        int gi = (bb * 32 + og + o) * 256 + tid;
        float blend = 0.5f * hv[o] + 0.5f * acc[o];
        float nf2 = pf[o] + blend;
        float nr2 = pr[o] - blend;
        f_hat[gi] = nf2; f_rest[gi] = nr2;
        fh_s[o][tid] = nf2; fr_s[o][tid] = nr2;
    }
    __syncthreads();

    for (int e = tid; e < 8 * npx; e += 256) {
        int o = e & 7, n = e >> 3;
        int y = n / pn, x = n - y * pn;
        int sh = (y * HH) / pn, eh = ((y + 1) * HH + pn - 1) / pn;
        int sw = (x * HH) / pn, ew = ((x + 1) * HH + pn - 1) / pn;
        float s = 0.f;
        for (int yy = sh; yy < eh; ++yy)
            for (int xx = sw; xx < ew; ++xx) s += fh_s[o][yy * 16 + xx];
        out[((bb * 680) + off + n) * 32 + og + o] = s * (1.f / (float)((eh - sh) * (ew - sw)));
    }

    if (pn2 > 0) {
        int npx2 = pn2 * pn2;
        for (int e = tid; e < 8 * npx2; e += 256) {
            int o = e / npx2, n = e - o * npx2;
            int y = n / pn2, x = n - y * pn2;
            int sh = (y * HH) / pn2, eh = ((y + 1) * HH + pn2 - 1) / pn2;
            int sw = (x * HH) / pn2, ew = ((x + 1) * HH + pn2 - 1) / pn2;
            float s = 0.f;
            for (int yy = sh; yy < eh; ++yy)
                for (int xx = sw; xx < ew; ++xx) s += fr_s[o][yy * 16 + xx];
            znext[(bb * 32 + og + o) * npx2 + n] = s * (1.f / (float)((eh - sh) * (ew - sw)));
        }
    }
}

// ---------------- launch ----------------

extern "C" void kernel_launch(void* const* d_in, const int* in_sizes, int n_in,
                              void* d_out, int out_size, void* d_ws, size_t ws_size,
                              hipStream_t stream) {
    const float* feat = (const float*)d_in[0];
    const float* cb   = (const float*)d_in[1];
    const float* phiw = (const float*)d_in[2];
    const float* phib = (const float*)d_in[3];
    float* out = (float*)d_out;
    float* wsf = (float*)d_ws;

    const int NE = B * C * HH * HH; // 1048576
    float* f_rest = wsf;
    float* f_hat  = wsf + NE;
    float* zA     = wsf + 2 * NE;
    float* zB     = wsf + 3 * NE;
    char*  tl     = (char*)(wsf + 4 * NE);
    double* c2d  = (double*)tl;                             // 32 KB
    float*  c2f  = (float*)(tl + (32 << 10));               // 16 KB
    float*  pb1  = (float*)(tl + (48 << 10));               // 1 MB each
    float*  pb2  = (float*)(tl + (48 << 10) + (1 << 20));
    int*    pi1  = (int*)  (tl + (48 << 10) + (2 << 20));
    unsigned short* cbh = (unsigned short*)(tl + (48 << 10) + (3 << 20));        // 256 KB
    unsigned short* cbl = (unsigned short*)(tl + (48 << 10) + (3 << 20) + (512 << 10));

    static const int PN_[10]   = {1, 2, 3, 4, 5, 6, 8, 10, 13, 16};
    static const int PI_[10]   = {0, 0, 1, 1, 1, 2, 2, 2, 3, 3};
    static const int OFF_[10]  = {0, 1, 5, 14, 30, 55, 91, 155, 255, 424};
    static const int NSEG_[10] = {32, 32, 32, 16, 16, 16, 8, 8, 4, 4};

    setup_kernel<<<dim3((NE + 255) / 256), dim3(256), 0, stream>>>(
        feat, f_rest, f_hat, cb, c2d, c2f, zA, cbh, cbl);

    for (int si = 0; si < 10; ++si) {
        int pn = PN_[si], npx = pn * pn;
        int tokens = B * npx;
        int nseg = NSEG_[si];
        int ngrp = tokens / 32;
        int njobs = ngrp * nseg;         // divisible by 4 at every stage
        float* zin  = (si & 1) ? zB : zA;
        float* zout = (si & 1) ? zA : zB;

        scan_mfma_kernel<<<dim3(njobs / 4), dim3(256), 0, stream>>>(
            zin, cbh, cbl, c2f, pb1, pb2, pi1, npx, nseg, ngrp);

        int pn2 = (si < 9) ? PN_[si + 1] : 0;
        stage_tail_kernel<<<dim3(B * 4), dim3(256), 0, stream>>>(
            pb1, pb2, pi1, zin, cb, c2d,
            phiw + PI_[si] * C * C * 9, phib + PI_[si] * C,
            f_hat, f_rest, out, zout, pn, OFF_[si], pn2, nseg);
    }
}

// Round 18
// 896.206 us; speedup vs baseline: 1.0246x; 1.0220x over previous
//
#include <hip/hip_runtime.h>

#define B 128
#define C 32
#define HH 16
#define V 4096
#define MARGIN 2e-4f

typedef __attribute__((ext_vector_type(8))) short bf16x8;
typedef __attribute__((ext_vector_type(4))) float f32x4;

// ---------------- helpers ----------------

__device__ __forceinline__ float cubicw(float t) {
    float at = fabsf(t);
    float at2 = at * at, at3 = at2 * at;
    if (at <= 1.f) return 1.25f * at3 - 2.25f * at2 + 1.f;
    if (at < 2.f)  return -0.75f * at3 + 3.75f * at2 - 6.f * at + 3.f;
    return 0.f;
}

__device__ __forceinline__ unsigned short f2bf_rne(float f) {
    unsigned int u = __float_as_uint(f);
    unsigned int r = (u + 0x7fffu + ((u >> 16) & 1u)) >> 16;
    return (unsigned short)r;
}
__device__ __forceinline__ float bf2f(unsigned short h) {
    return __uint_as_float(((unsigned int)h) << 16);
}

// ---------------- kernels ----------------

// setup: f_rest=feat, f_hat=0, c2 (fp64+fp32), stage-0 z, codebook bf16 hi/lo frag tables
// frag layout: elem i -> ii=i&7, nn=(i>>3)&15, kb=(i>>7)&3, T=i>>9; code v=T*16+nn, k=kb*8+ii
__global__ void setup_kernel(const float* __restrict__ feat, float* __restrict__ f_rest,
                             float* __restrict__ f_hat, const float* __restrict__ cb,
                             double* __restrict__ c2d, float* __restrict__ c2f,
                             float* __restrict__ z0, unsigned short* __restrict__ cbh,
                             unsigned short* __restrict__ cbl) {
    int i = blockIdx.x * 256 + threadIdx.x;
    if (i < B * C * HH * HH) { f_rest[i] = feat[i]; f_hat[i] = 0.f; }
    if (i < V) {
        const float* p = cb + i * C;
        double s = 0.0;
        #pragma unroll
        for (int j = 0; j < C; ++j) { double d = (double)p[j]; s = fma(d, d, s); }
        c2d[i] = s;
        c2f[i] = (float)s;
    }
    if (i < B * C) {
        const float* p = feat + i * (HH * HH);
        float s = 0.f;
        for (int px = 0; px < HH * HH; ++px) s += p[px];
        z0[i] = s * (1.f / 256.f);
    }
    if (i < V * C) {
        int ii = i & 7, nn = (i >> 3) & 15, kb = (i >> 7) & 3, T = i >> 9;
        float val = cb[(T * 16 + nn) * C + kb * 8 + ii];
        unsigned short h = f2bf_rne(val);
        cbh[i] = h;
        cbl[i] = f2bf_rne(val - bf2f(h));
    }
}

// ---- MFMA top-2 scan v3: waves_per_eu(2,4) bounds occupancy FROM ABOVE so the
// register allocator stops remat-ing to chase 8 waves/EU (R6..R17: VGPR stuck at
// 36-88 across every structure). Explicit next-tile prefetch hides L2 latency. ----
__global__ __launch_bounds__(256) __attribute__((amdgpu_waves_per_eu(2, 4)))
void scan_mfma_kernel(
    const float* __restrict__ z, const unsigned short* __restrict__ cbh,
    const unsigned short* __restrict__ cbl, const float* __restrict__ c2f,
    float* __restrict__ pb1, float* __restrict__ pb2, int* __restrict__ pi1,
    int npx, int nseg, int ngrp)
{
    int tid = threadIdx.x;
    int wave = tid >> 6, lane = tid & 63;
    int job = blockIdx.x * 4 + wave;
    int seg = job / ngrp, tokgrp = job - seg * ngrp;
    int cps = V / nseg;
    int total = B * npx;
    int tn = lane & 15, kb = lane >> 4;

    // union: frag store during loop (16 KB), merge arrays after (26.1 KB)
    __shared__ alignas(16) char ldsu[26112];
    short* ldsA = (short*)ldsu;                 // frag-major: [(wave*4+f)*64+lane] x 8 shorts
    float* smb1 = (float*)ldsu;                 // [4][32*17]
    float* smb2 = (float*)(ldsu + 8704);
    int*   smi1 = (int*)(ldsu + 17408);

    // build this lane's 4 fragments into LDS (one-time)
    {
        #pragma unroll
        for (int g = 0; g < 2; ++g) {
            int tok = tokgrp * 32 + g * 16 + tn;
            int bq = tok / npx, n = tok - bq * npx;
            short hi[8], lo[8];
            #pragma unroll
            for (int i = 0; i < 8; ++i) {
                float v = z[(bq * C + kb * 8 + i) * npx + n];
                unsigned short h = f2bf_rne(v);
                hi[i] = (short)h;
                lo[i] = (short)f2bf_rne(v - bf2f(h));
            }
            short* sh_ = ldsA + ((wave * 4 + g * 2) * 64 + lane) * 8;
            short* sl_ = ldsA + ((wave * 4 + g * 2 + 1) * 64 + lane) * 8;
            #pragma unroll
            for (int i = 0; i < 8; ++i) { sh_[i] = hi[i]; sl_[i] = lo[i]; }
        }
    }
    __syncthreads();

    const bf16x8* fp = reinterpret_cast<const bf16x8*>(ldsA);
    bf16x8 a0h = fp[(wave * 4 + 0) * 64 + lane];
    bf16x8 a0l = fp[(wave * 4 + 1) * 64 + lane];
    bf16x8 a1h = fp[(wave * 4 + 2) * 64 + lane];
    bf16x8 a1l = fp[(wave * 4 + 3) * 64 + lane];

    const bf16x8* ph = reinterpret_cast<const bf16x8*>(cbh);
    const bf16x8* pl = reinterpret_cast<const bf16x8*>(cbl);

    float b1[8], b2[8]; int i1[8];
    #pragma unroll
    for (int s = 0; s < 8; ++s) { b1[s] = 3e38f; b2[s] = 3e38f; i1[s] = 0; }

    int T0 = seg * (cps >> 4), nT = cps >> 4;
    bf16x8 bh = ph[(size_t)T0 * 64 + lane];
    bf16x8 bl = pl[(size_t)T0 * 64 + lane];
    float c2v = c2f[T0 * 16 + tn];

    #pragma unroll 1
    for (int t = 0; t < nT; ++t) {
        // prefetch next tile (clamped) before compute: L2 latency hides under MFMAs
        int Tn = T0 + ((t + 1 < nT) ? t + 1 : t);
        bf16x8 nbh = ph[(size_t)Tn * 64 + lane];
        bf16x8 nbl = pl[(size_t)Tn * 64 + lane];
        float nc2 = c2f[Tn * 16 + tn];

        f32x4 a0 = {0.f, 0.f, 0.f, 0.f}, a1 = {0.f, 0.f, 0.f, 0.f};
        a0 = __builtin_amdgcn_mfma_f32_16x16x32_bf16(a0h, bh, a0, 0, 0, 0);
        a0 = __builtin_amdgcn_mfma_f32_16x16x32_bf16(a0l, bh, a0, 0, 0, 0);
        a0 = __builtin_amdgcn_mfma_f32_16x16x32_bf16(a0h, bl, a0, 0, 0, 0);
        a0 = __builtin_amdgcn_mfma_f32_16x16x32_bf16(a0l, bl, a0, 0, 0, 0);
        a1 = __builtin_amdgcn_mfma_f32_16x16x32_bf16(a1h, bh, a1, 0, 0, 0);
        a1 = __builtin_amdgcn_mfma_f32_16x16x32_bf16(a1l, bh, a1, 0, 0, 0);
        a1 = __builtin_amdgcn_mfma_f32_16x16x32_bf16(a1h, bl, a1, 0, 0, 0);
        a1 = __builtin_amdgcn_mfma_f32_16x16x32_bf16(a1l, bl, a1, 0, 0, 0);

        int code = (T0 + t) * 16 + tn;   // ascending with t -> strict < keeps lowest idx
        #pragma unroll
        for (int r = 0; r < 4; ++r) {
            float s0 = fmaf(-2.f, a0[r], c2v);
            if (s0 < b1[r]) { b2[r] = b1[r]; b1[r] = s0; i1[r] = code; }
            else if (s0 < b2[r]) { b2[r] = s0; }
            float s1 = fmaf(-2.f, a1[r], c2v);
            if (s1 < b1[4 + r]) { b2[4 + r] = b1[4 + r]; b1[4 + r] = s1; i1[4 + r] = code; }
            else if (s1 < b2[4 + r]) { b2[4 + r] = s1; }
        }
        bh = nbh; bl = nbl; c2v = nc2;
    }

    __syncthreads();   // frag region dead -> merge overlay (stride 17: conflict-free)
    #pragma unroll
    for (int g = 0; g < 2; ++g)
        #pragma unroll
        for (int r = 0; r < 4; ++r) {
            int tokl = g * 16 + kb * 4 + r;
            int base = wave * 544 + tokl * 17 + tn;
            smb1[base] = b1[g * 4 + r];
            smb2[base] = b2[g * 4 + r];
            smi1[base] = i1[g * 4 + r];
        }
    __syncthreads();
    if (tid < 128) {
        int w = tid >> 5, tl = tid & 31;
        int jobw = blockIdx.x * 4 + w;
        int segw = jobw / ngrp, tgw = jobw - segw * ngrp;
        float gb1 = 3e38f, gb2 = 3e38f; int gi1 = 0;
        #pragma unroll
        for (int i = 0; i < 16; ++i) {
            float v1 = smb1[w * 544 + tl * 17 + i];
            int   ix = smi1[w * 544 + tl * 17 + i];
            if (v1 < gb1 || (v1 == gb1 && ix < gi1)) { gb2 = gb1; gb1 = v1; gi1 = ix; }
            else if (v1 < gb2) { gb2 = v1; }
            float v2 = smb2[w * 544 + tl * 17 + i];
            if (v2 < gb2) gb2 = v2;
        }
        int tok = tgw * 32 + tl;
        pb1[(size_t)segw * total + tok] = gb1;
        pb2[(size_t)segw * total + tok] = gb2;
        pi1[(size_t)segw * total + tok] = gi1;
    }
}

// fused tail (R15, unchanged): combine + fp64 recheck + gather + separable bicubic
//                              + conv + blend/update + context pool + next-z pool
__global__ __launch_bounds__(256) void stage_tail_kernel(
    const float* __restrict__ pb1, const float* __restrict__ pb2,
    const int* __restrict__ pi1, const float* __restrict__ z,
    const float* __restrict__ cb, const double* __restrict__ c2d,
    const float* __restrict__ w, const float* __restrict__ bias,
    float* __restrict__ f_hat, float* __restrict__ f_rest,
    float* __restrict__ out, float* __restrict__ znext,
    int pn, int off, int pn2, int nseg)
{
    int bb = blockIdx.x >> 2;
    int og = (blockIdx.x & 3) * 8;
    int tid = threadIdx.x;
    int npx = pn * pn;
    int total = B * npx;

    __shared__ float A_s[32][260];
    __shared__ float B_s[32][260];
    __shared__ int idx_s[256];
    __shared__ int flist[256];
    __shared__ int fcnt;
    __shared__ double zsd[C];
    __shared__ double sred[256];
    __shared__ int sidx[256];
    __shared__ float wtab[16][4];
    __shared__ int   itab[16][4];
    float (*fh_s)[260] = &B_s[0];
    float (*fr_s)[260] = &B_s[8];

    float pf[8], pr[8];
    #pragma unroll
    for (int o = 0; o < 8; ++o) {
        int gi = (bb * 32 + og + o) * 256 + tid;
        pf[o] = f_hat[gi]; pr[o] = f_rest[gi];
    }

    if (tid < 16) {
        float scale = (float)pn * (1.f / 16.f);
        float src = (tid + 0.5f) * scale - 0.5f;
        int fi = (int)floorf(src);
        float t = src - (float)fi;
        #pragma unroll
        for (int k = 0; k < 4; ++k) {
            wtab[tid][k] = cubicw((float)(k - 1) - t);
            itab[tid][k] = min(max(fi + k - 1, 0), pn - 1);
        }
    }
    if (tid == 0) fcnt = 0;
    __syncthreads();

    if (tid < npx) {
        int tok = bb * npx + tid;
        float gb1 = 3e38f, gb2 = 3e38f; int gi1 = 0;
        for (int s = 0; s < nseg; ++s) {
            float v1 = pb1[(size_t)s * total + tok];
            int   ix = pi1[(size_t)s * total + tok];
            if (v1 < gb1 || (v1 == gb1 && ix < gi1)) { gb2 = gb1; gb1 = v1; gi1 = ix; }
            else if (v1 < gb2) { gb2 = v1; }
            float v2 = pb2[(size_t)s * total + tok];
            if (v2 < gb2) gb2 = v2;
        }
        idx_s[tid] = gi1;
        if (gb2 - gb1 < MARGIN) { int slot = atomicAdd(&fcnt, 1); flist[slot] = tid; }
    }
    __syncthreads();

    int nf = fcnt;
    for (int f = 0; f < nf; ++f) {
        int n = flist[f];
        if (tid < C) zsd[tid] = (double)z[(bb * C + tid) * npx + n];
        __syncthreads();
        double best = 1e300; int bi = 0x7fffffff;
        for (int k = 0; k < V / 256; ++k) {
            int v = tid + k * 256;
            const float4* cp = reinterpret_cast<const float4*>(cb + (size_t)v * C);
            double acc = 0.0;
            #pragma unroll
            for (int qq = 0; qq < 8; ++qq) {
                float4 fv = cp[qq];
                acc = fma((double)fv.x, zsd[4 * qq + 0], acc);
                acc = fma((double)fv.y, zsd[4 * qq + 1], acc);
                acc = fma((double)fv.z, zsd[4 * qq + 2], acc);
                acc = fma((double)fv.w, zsd[4 * qq + 3], acc);
            }
            double s = fma(-2.0, acc, c2d[v]);
            if (s < best || (s == best && v < bi)) { best = s; bi = v; }
        }
        sred[tid] = best; sidx[tid] = bi;
        __syncthreads();
        for (int st = 128; st > 0; st >>= 1) {
            if (tid < st) {
                double o = sred[tid + st]; int oi = sidx[tid + st];
                double me = sred[tid];     int mi = sidx[tid];
                if (o < me || (o == me && oi < mi)) { sred[tid] = o; sidx[tid] = oi; }
            }
            __syncthreads();
        }
        if (tid == 0) idx_s[n] = sidx[0];
        __syncthreads();
    }
    __syncthreads();

    for (int e = tid; e < 32 * npx; e += 256) {
        int c = e & 31, n = e >> 5;
        A_s[c][n] = cb[idx_s[n] * 32 + c];
    }
    __syncthreads();

    for (int e = tid; e < 32 * 16 * pn; e += 256) {
        int wx = e % pn; int rest = e / pn;
        int p = rest & 15, c = rest >> 4;
        float s = 0.f;
        #pragma unroll
        for (int k = 0; k < 4; ++k)
            s = fmaf(wtab[p][k], A_s[c][itab[p][k] * pn + wx], s);
        B_s[c][p * pn + wx] = s;
    }
    __syncthreads();

    #pragma unroll
    for (int it = 0; it < 32; ++it) {
        int e = tid + it * 256;
        int q = e & 15, p = (e >> 4) & 15, c = e >> 8;
        float s = 0.f;
        #pragma unroll
        for (int k = 0; k < 4; ++k)
            s = fmaf(wtab[q][k], B_s[c][p * pn + itab[q][k]], s);
        A_s[c][e & 255] = s;
    }
    __syncthreads();

    int p = tid >> 4, q = tid & 15;
    float acc[8];
    #pragma unroll
    for (int o = 0; o < 8; ++o) acc[o] = bias[og + o];
    for (int i = 0; i < 32; ++i) {
        float v[9];
        #pragma unroll
        for (int dy = 0; dy < 3; ++dy)
            #pragma unroll
            for (int dx = 0; dx < 3; ++dx) {
                int pp = p + dy - 1, qq = q + dx - 1;
                bool in = (pp >= 0) & (pp < 16) & (qq >= 0) & (qq < 16);
                v[dy * 3 + dx] = in ? A_s[i][pp * 16 + qq] : 0.f;
            }
        #pragma unroll
        for (int o = 0; o < 8; ++o) {
            const float* wp_ = w + ((og + o) * 32 + i) * 9;
            #pragma unroll
            for (int k = 0; k < 9; ++k) acc[o] = fmaf(wp_[k], v[k], acc[o]);
        }
    }
    float hv[8];
    #pragma unroll
    for (int o = 0; o < 8; ++o) hv[o] = A_s[og + o][tid];
    __syncthreads();

    #pragma unroll
    for (int o = 0; o < 8; ++o) {
        int gi = (bb * 32 + og + o) * 256 + tid;
        float blend = 0.5f * hv[o] + 0.5f * acc[o];
        float nf2 = pf[o] + blend;
        float nr2 = pr[o] - blend;
        f_hat[gi] = nf2; f_rest[gi] = nr2;
        fh_s[o][tid] = nf2; fr_s[o][tid] = nr2;
    }
    __syncthreads();

    for (int e = tid; e < 8 * npx; e += 256) {
        int o = e & 7, n = e >> 3;
        int y = n / pn, x = n - y * pn;
        int sh = (y * HH) / pn, eh = ((y + 1) * HH + pn - 1) / pn;
        int sw = (x * HH) / pn, ew = ((x + 1) * HH + pn - 1) / pn;
        float s = 0.f;
        for (int yy = sh; yy < eh; ++yy)
            for (int xx = sw; xx < ew; ++xx) s += fh_s[o][yy * 16 + xx];
        out[((bb * 680) + off + n) * 32 + og + o] = s * (1.f / (float)((eh - sh) * (ew - sw)));
    }

    if (pn2 > 0) {
        int npx2 = pn2 * pn2;
        for (int e = tid; e < 8 * npx2; e += 256) {
            int o = e / npx2, n = e - o * npx2;
            int y = n / pn2, x = n - y * pn2;
            int sh = (y * HH) / pn2, eh = ((y + 1) * HH + pn2 - 1) / pn2;
            int sw = (x * HH) / pn2, ew = ((x + 1) * HH + pn2 - 1) / pn2;
            float s = 0.f;
            for (int yy = sh; yy < eh; ++yy)
                for (int xx = sw; xx < ew; ++xx) s += fr_s[o][yy * 16 + xx];
            znext[(bb * 32 + og + o) * npx2 + n] = s * (1.f / (float)((eh - sh) * (ew - sw)));
        }
    }
}

// ---------------- launch ----------------

extern "C" void kernel_launch(void* const* d_in, const int* in_sizes, int n_in,
                              void* d_out, int out_size, void* d_ws, size_t ws_size,
                              hipStream_t stream) {
    const float* feat = (const float*)d_in[0];
    const float* cb   = (const float*)d_in[1];
    const float* phiw = (const float*)d_in[2];
    const float* phib = (const float*)d_in[3];
    float* out = (float*)d_out;
    float* wsf = (float*)d_ws;

    const int NE = B * C * HH * HH; // 1048576
    float* f_rest = wsf;
    float* f_hat  = wsf + NE;
    float* zA     = wsf + 2 * NE;
    float* zB     = wsf + 3 * NE;
    char*  tl     = (char*)(wsf + 4 * NE);
    double* c2d  = (double*)tl;                             // 32 KB
    float*  c2f  = (float*)(tl + (32 << 10));               // 16 KB
    float*  pb1  = (float*)(tl + (48 << 10));               // 1 MB each
    float*  pb2  = (float*)(tl + (48 << 10) + (1 << 20));
    int*    pi1  = (int*)  (tl + (48 << 10) + (2 << 20));
    unsigned short* cbh = (unsigned short*)(tl + (48 << 10) + (3 << 20));        // 256 KB
    unsigned short* cbl = (unsigned short*)(tl + (48 << 10) + (3 << 20) + (512 << 10));

    static const int PN_[10]   = {1, 2, 3, 4, 5, 6, 8, 10, 13, 16};
    static const int PI_[10]   = {0, 0, 1, 1, 1, 2, 2, 2, 3, 3};
    static const int OFF_[10]  = {0, 1, 5, 14, 30, 55, 91, 155, 255, 424};
    static const int NSEG_[10] = {32, 32, 32, 16, 16, 16, 8, 8, 4, 4};

    setup_kernel<<<dim3((NE + 255) / 256), dim3(256), 0, stream>>>(
        feat, f_rest, f_hat, cb, c2d, c2f, zA, cbh, cbl);

    for (int si = 0; si < 10; ++si) {
        int pn = PN_[si], npx = pn * pn;
        int tokens = B * npx;
        int nseg = NSEG_[si];
        int ngrp = tokens / 32;
        int njobs = ngrp * nseg;         // divisible by 4 at every stage
        float* zin  = (si & 1) ? zB : zA;
        float* zout = (si & 1) ? zA : zB;

        scan_mfma_kernel<<<dim3(njobs / 4), dim3(256), 0, stream>>>(
            zin, cbh, cbl, c2f, pb1, pb2, pi1, npx, nseg, ngrp);

        int pn2 = (si < 9) ? PN_[si + 1] : 0;
        stage_tail_kernel<<<dim3(B * 4), dim3(256), 0, stream>>>(
            pb1, pb2, pi1, zin, cb, c2d,
            phiw + PI_[si] * C * C * 9, phib + PI_[si] * C,
            f_hat, f_rest, out, zout, pn, OFF_[si], pn2, nseg);
    }
}

// Round 19
// 871.932 us; speedup vs baseline: 1.0531x; 1.0278x over previous
//
#include <hip/hip_runtime.h>

#define B 128
#define C 32
#define HH 16
#define V 4096
#define MARGIN 1e-4f

typedef __attribute__((ext_vector_type(8))) short bf16x8;
typedef __attribute__((ext_vector_type(4))) float f32x4;

// ---------------- helpers ----------------

__device__ __forceinline__ float cubicw(float t) {
    float at = fabsf(t);
    float at2 = at * at, at3 = at2 * at;
    if (at <= 1.f) return 1.25f * at3 - 2.25f * at2 + 1.f;
    if (at < 2.f)  return -0.75f * at3 + 3.75f * at2 - 6.f * at + 3.f;
    return 0.f;
}

__device__ __forceinline__ unsigned short f2bf_rne(float f) {
    unsigned int u = __float_as_uint(f);
    unsigned int r = (u + 0x7fffu + ((u >> 16) & 1u)) >> 16;
    return (unsigned short)r;
}
__device__ __forceinline__ float bf2f(unsigned short h) {
    return __uint_as_float(((unsigned int)h) << 16);
}

// ---------------- kernels ----------------

// setup: f_rest=feat, f_hat=0, c2 (fp64+fp32), stage-0 z, codebook bf16 hi/lo frag tables
__global__ void setup_kernel(const float* __restrict__ feat, float* __restrict__ f_rest,
                             float* __restrict__ f_hat, const float* __restrict__ cb,
                             double* __restrict__ c2d, float* __restrict__ c2f,
                             float* __restrict__ z0, unsigned short* __restrict__ cbh,
                             unsigned short* __restrict__ cbl) {
    int i = blockIdx.x * 256 + threadIdx.x;
    if (i < B * C * HH * HH) { f_rest[i] = feat[i]; f_hat[i] = 0.f; }
    if (i < V) {
        const float* p = cb + i * C;
        double s = 0.0;
        #pragma unroll
        for (int j = 0; j < C; ++j) { double d = (double)p[j]; s = fma(d, d, s); }
        c2d[i] = s;
        c2f[i] = (float)s;
    }
    if (i < B * C) {
        const float* p = feat + i * (HH * HH);
        float s = 0.f;
        for (int px = 0; px < HH * HH; ++px) s += p[px];
        z0[i] = s * (1.f / 256.f);
    }
    if (i < V * C) {
        int ii = i & 7, nn = (i >> 3) & 15, kb = (i >> 7) & 3, T = i >> 9;
        float val = cb[(T * 16 + nn) * C + kb * 8 + ii];
        unsigned short h = f2bf_rne(val);
        cbh[i] = h;
        cbl[i] = f2bf_rne(val - bf2f(h));
    }
}

// ---- MFMA top-2 scan v4: A-fragments re-read from LDS EVERY TILE behind an
// asm memory clobber. R16-R18 post-mortems: z is const __restrict__, so the
// compiler "spills" frag registers by re-loading z + re-converting per tile
// (~600 VALU/tile, VALUBusy 90%). The clobber breaks provenance: LDS contents
// become unknowable, forcing 4 cheap ds_read_b128/tile instead. ----
__global__ __launch_bounds__(256, 4) void scan_mfma_kernel(
    const float* __restrict__ z, const unsigned short* __restrict__ cbh,
    const unsigned short* __restrict__ cbl, const float* __restrict__ c2f,
    float* __restrict__ pb1, float* __restrict__ pb2, int* __restrict__ pi1,
    int npx, int nseg, int ngrp)
{
    int tid = threadIdx.x;
    int wave = tid >> 6, lane = tid & 63;
    int job = blockIdx.x * 4 + wave;
    int seg = job / ngrp, tokgrp = job - seg * ngrp;
    int cps = V / nseg;
    int total = B * npx;
    int tn = lane & 15, kb = lane >> 4;

    // union: frag store during loop (16 KB), merge arrays after (26.1 KB)
    __shared__ alignas(16) char ldsu[26112];
    short* ldsA = (short*)ldsu;                 // [(wave*4+f)*64+lane] x 8 shorts
    float* smb1 = (float*)ldsu;                 // [4][32*17]
    float* smb2 = (float*)(ldsu + 8704);
    int*   smi1 = (int*)(ldsu + 17408);

    // build this lane's 4 fragments into LDS (one-time)
    {
        #pragma unroll
        for (int g = 0; g < 2; ++g) {
            int tok = tokgrp * 32 + g * 16 + tn;
            int bq = tok / npx, n = tok - bq * npx;
            short hi[8], lo[8];
            #pragma unroll
            for (int i = 0; i < 8; ++i) {
                float v = z[(bq * C + kb * 8 + i) * npx + n];
                unsigned short h = f2bf_rne(v);
                hi[i] = (short)h;
                lo[i] = (short)f2bf_rne(v - bf2f(h));
            }
            short* sh_ = ldsA + ((wave * 4 + g * 2) * 64 + lane) * 8;
            short* sl_ = ldsA + ((wave * 4 + g * 2 + 1) * 64 + lane) * 8;
            #pragma unroll
            for (int i = 0; i < 8; ++i) { sh_[i] = hi[i]; sl_[i] = lo[i]; }
        }
    }
    __syncthreads();

    const bf16x8* fp = reinterpret_cast<const bf16x8*>(ldsA);
    const bf16x8* ph = reinterpret_cast<const bf16x8*>(cbh);
    const bf16x8* pl = reinterpret_cast<const bf16x8*>(cbl);

    float b1[8], b2[8]; int i1[8];
    #pragma unroll
    for (int s = 0; s < 8; ++s) { b1[s] = 3e38f; b2[s] = 3e38f; i1[s] = 0; }

    int T0 = seg * (cps >> 4), nT = cps >> 4;
    bf16x8 bh = ph[(size_t)T0 * 64 + lane];
    bf16x8 bl = pl[(size_t)T0 * 64 + lane];
    float c2v = c2f[T0 * 16 + tn];

    #pragma unroll 1
    for (int t = 0; t < nT; ++t) {
        asm volatile("" ::: "memory");   // LDS unknowable -> frags must be ds_read, not remat'd
        bf16x8 a0h = fp[(wave * 4 + 0) * 64 + lane];
        bf16x8 a0l = fp[(wave * 4 + 1) * 64 + lane];
        bf16x8 a1h = fp[(wave * 4 + 2) * 64 + lane];
        bf16x8 a1l = fp[(wave * 4 + 3) * 64 + lane];

        // prefetch next tile (clamped): L2 latency hides under MFMAs
        int Tn = T0 + ((t + 1 < nT) ? t + 1 : t);
        bf16x8 nbh = ph[(size_t)Tn * 64 + lane];
        bf16x8 nbl = pl[(size_t)Tn * 64 + lane];
        float nc2 = c2f[Tn * 16 + tn];

        f32x4 a0 = {0.f, 0.f, 0.f, 0.f}, a1 = {0.f, 0.f, 0.f, 0.f};
        a0 = __builtin_amdgcn_mfma_f32_16x16x32_bf16(a0h, bh, a0, 0, 0, 0);
        a0 = __builtin_amdgcn_mfma_f32_16x16x32_bf16(a0l, bh, a0, 0, 0, 0);
        a0 = __builtin_amdgcn_mfma_f32_16x16x32_bf16(a0h, bl, a0, 0, 0, 0);
        a0 = __builtin_amdgcn_mfma_f32_16x16x32_bf16(a0l, bl, a0, 0, 0, 0);
        a1 = __builtin_amdgcn_mfma_f32_16x16x32_bf16(a1h, bh, a1, 0, 0, 0);
        a1 = __builtin_amdgcn_mfma_f32_16x16x32_bf16(a1l, bh, a1, 0, 0, 0);
        a1 = __builtin_amdgcn_mfma_f32_16x16x32_bf16(a1h, bl, a1, 0, 0, 0);
        a1 = __builtin_amdgcn_mfma_f32_16x16x32_bf16(a1l, bl, a1, 0, 0, 0);

        int code = (T0 + t) * 16 + tn;   // ascending with t -> strict < keeps lowest idx
        #pragma unroll
        for (int r = 0; r < 4; ++r) {
            float s0 = fmaf(-2.f, a0[r], c2v);
            if (s0 < b1[r]) { b2[r] = b1[r]; b1[r] = s0; i1[r] = code; }
            else if (s0 < b2[r]) { b2[r] = s0; }
            float s1 = fmaf(-2.f, a1[r], c2v);
            if (s1 < b1[4 + r]) { b2[4 + r] = b1[4 + r]; b1[4 + r] = s1; i1[4 + r] = code; }
            else if (s1 < b2[4 + r]) { b2[4 + r] = s1; }
        }
        bh = nbh; bl = nbl; c2v = nc2;
    }

    __syncthreads();   // frag region dead -> merge overlay (stride 17: conflict-free)
    #pragma unroll
    for (int g = 0; g < 2; ++g)
        #pragma unroll
        for (int r = 0; r < 4; ++r) {
            int tokl = g * 16 + kb * 4 + r;
            int base = wave * 544 + tokl * 17 + tn;
            smb1[base] = b1[g * 4 + r];
            smb2[base] = b2[g * 4 + r];
            smi1[base] = i1[g * 4 + r];
        }
    __syncthreads();
    if (tid < 128) {
        int w = tid >> 5, tl = tid & 31;
        int jobw = blockIdx.x * 4 + w;
        int segw = jobw / ngrp, tgw = jobw - segw * ngrp;
        float gb1 = 3e38f, gb2 = 3e38f; int gi1 = 0;
        #pragma unroll
        for (int i = 0; i < 16; ++i) {
            float v1 = smb1[w * 544 + tl * 17 + i];
            int   ix = smi1[w * 544 + tl * 17 + i];
            if (v1 < gb1 || (v1 == gb1 && ix < gi1)) { gb2 = gb1; gb1 = v1; gi1 = ix; }
            else if (v1 < gb2) { gb2 = v1; }
            float v2 = smb2[w * 544 + tl * 17 + i];
            if (v2 < gb2) gb2 = v2;
        }
        int tok = tgw * 32 + tl;
        pb1[(size_t)segw * total + tok] = gb1;
        pb2[(size_t)segw * total + tok] = gb2;
        pi1[(size_t)segw * total + tok] = gi1;
    }
}

// fused tail v3: LDS cut to ~45 KB (bicubic temp chunked 8ch; fh/fr overlay A_s)
// -> 3 blocks/CU (was 2).  combine + fp64 recheck + gather + separable bicubic
// + conv + blend/update + context pool + next-z pool.
__global__ __launch_bounds__(256) void stage_tail_kernel(
    const float* __restrict__ pb1, const float* __restrict__ pb2,
    const int* __restrict__ pi1, const float* __restrict__ z,
    const float* __restrict__ cb, const double* __restrict__ c2d,
    const float* __restrict__ w, const float* __restrict__ bias,
    float* __restrict__ f_hat, float* __restrict__ f_rest,
    float* __restrict__ out, float* __restrict__ znext,
    int pn, int off, int pn2, int nseg)
{
    int bb = blockIdx.x >> 2;
    int og = (blockIdx.x & 3) * 8;
    int tid = threadIdx.x;
    int npx = pn * pn;
    int total = B * npx;

    __shared__ float A_s[32][257];    // gather -> hu -> (rows 0..15) fh/fr overlay
    __shared__ float Bc[8][257];      // bicubic v-pass temp, 8-channel chunks
    __shared__ int idx_s[256];
    __shared__ int flist[256];
    __shared__ int fcnt;
    __shared__ double zsd[C];
    __shared__ double sred[256];
    __shared__ int sidx[256];
    __shared__ float wtab[16][4];
    __shared__ int   itab[16][4];
    float (*fh_s)[257] = &A_s[0];
    float (*fr_s)[257] = &A_s[8];

    float pf[8], pr[8];
    #pragma unroll
    for (int o = 0; o < 8; ++o) {
        int gi = (bb * 32 + og + o) * 256 + tid;
        pf[o] = f_hat[gi]; pr[o] = f_rest[gi];
    }

    if (tid < 16) {
        float scale = (float)pn * (1.f / 16.f);
        float src = (tid + 0.5f) * scale - 0.5f;
        int fi = (int)floorf(src);
        float t = src - (float)fi;
        #pragma unroll
        for (int k = 0; k < 4; ++k) {
            wtab[tid][k] = cubicw((float)(k - 1) - t);
            itab[tid][k] = min(max(fi + k - 1, 0), pn - 1);
        }
    }
    if (tid == 0) fcnt = 0;
    __syncthreads();

    if (tid < npx) {
        int tok = bb * npx + tid;
        float gb1 = 3e38f, gb2 = 3e38f; int gi1 = 0;
        for (int s = 0; s < nseg; ++s) {
            float v1 = pb1[(size_t)s * total + tok];
            int   ix = pi1[(size_t)s * total + tok];
            if (v1 < gb1 || (v1 == gb1 && ix < gi1)) { gb2 = gb1; gb1 = v1; gi1 = ix; }
            else if (v1 < gb2) { gb2 = v1; }
            float v2 = pb2[(size_t)s * total + tok];
            if (v2 < gb2) gb2 = v2;
        }
        idx_s[tid] = gi1;
        if (gb2 - gb1 < MARGIN) { int slot = atomicAdd(&fcnt, 1); flist[slot] = tid; }
    }
    __syncthreads();

    int nf = fcnt;
    for (int f = 0; f < nf; ++f) {
        int n = flist[f];
        if (tid < C) zsd[tid] = (double)z[(bb * C + tid) * npx + n];
        __syncthreads();
        double best = 1e300; int bi = 0x7fffffff;
        for (int k = 0; k < V / 256; ++k) {
            int v = tid + k * 256;
            const float4* cp = reinterpret_cast<const float4*>(cb + (size_t)v * C);
            double acc = 0.0;
            #pragma unroll
            for (int qq = 0; qq < 8; ++qq) {
                float4 fv = cp[qq];
                acc = fma((double)fv.x, zsd[4 * qq + 0], acc);
                acc = fma((double)fv.y, zsd[4 * qq + 1], acc);
                acc = fma((double)fv.z, zsd[4 * qq + 2], acc);
                acc = fma((double)fv.w, zsd[4 * qq + 3], acc);
            }
            double s = fma(-2.0, acc, c2d[v]);
            if (s < best || (s == best && v < bi)) { best = s; bi = v; }
        }
        sred[tid] = best; sidx[tid] = bi;
        __syncthreads();
        for (int st = 128; st > 0; st >>= 1) {
            if (tid < st) {
                double o = sred[tid + st]; int oi = sidx[tid + st];
                double me = sred[tid];     int mi = sidx[tid];
                if (o < me || (o == me && oi < mi)) { sred[tid] = o; sidx[tid] = oi; }
            }
            __syncthreads();
        }
        if (tid == 0) idx_s[n] = sidx[0];
        __syncthreads();
    }
    __syncthreads();

    // gather: A_s[c][n] = cb[idx[n]][c]
    for (int e = tid; e < 32 * npx; e += 256) {
        int c = e & 31, n = e >> 5;
        A_s[c][n] = cb[idx_s[n] * 32 + c];
    }
    __syncthreads();

    // separable bicubic in 4 chunks of 8 channels (Bc = v-pass temp)
    #pragma unroll 1
    for (int ch = 0; ch < 4; ++ch) {
        for (int e = tid; e < 8 * 16 * pn; e += 256) {
            int wx = e % pn; int rest = e / pn;
            int p = rest & 15, cl = rest >> 4;
            float s = 0.f;
            #pragma unroll
            for (int k = 0; k < 4; ++k)
                s = fmaf(wtab[p][k], A_s[ch * 8 + cl][itab[p][k] * pn + wx], s);
            Bc[cl][p * pn + wx] = s;
        }
        __syncthreads();
        #pragma unroll
        for (int it = 0; it < 8; ++it) {
            int e = tid + it * 256;
            int q = e & 15, p = (e >> 4) & 15, cl = e >> 8;
            float s = 0.f;
            #pragma unroll
            for (int k = 0; k < 4; ++k)
                s = fmaf(wtab[q][k], Bc[cl][p * pn + itab[q][k]], s);
            A_s[ch * 8 + cl][e & 255] = s;
        }
        __syncthreads();
    }

    // conv 3x3 SAME over 32 in-ch (A_s = hu) for out-ch og..og+7
    int p = tid >> 4, q = tid & 15;
    float acc[8];
    #pragma unroll
    for (int o = 0; o < 8; ++o) acc[o] = bias[og + o];
    for (int i = 0; i < 32; ++i) {
        float v[9];
        #pragma unroll
        for (int dy = 0; dy < 3; ++dy)
            #pragma unroll
            for (int dx = 0; dx < 3; ++dx) {
                int pp = p + dy - 1, qq = q + dx - 1;
                bool in = (pp >= 0) & (pp < 16) & (qq >= 0) & (qq < 16);
                v[dy * 3 + dx] = in ? A_s[i][pp * 16 + qq] : 0.f;
            }
        #pragma unroll
        for (int o = 0; o < 8; ++o) {
            const float* wp_ = w + ((og + o) * 32 + i) * 9;
            #pragma unroll
            for (int k = 0; k < 9; ++k) acc[o] = fmaf(wp_[k], v[k], acc[o]);
        }
    }
    float hv[8];
    #pragma unroll
    for (int o = 0; o < 8; ++o) hv[o] = A_s[og + o][tid];
    __syncthreads();   // all A_s reads done before overlay writes

    #pragma unroll
    for (int o = 0; o < 8; ++o) {
        int gi = (bb * 32 + og + o) * 256 + tid;
        float blend = 0.5f * hv[o] + 0.5f * acc[o];
        float nf2 = pf[o] + blend;
        float nr2 = pr[o] - blend;
        f_hat[gi] = nf2; f_rest[gi] = nr2;
        fh_s[o][tid] = nf2; fr_s[o][tid] = nr2;
    }
    __syncthreads();

    for (int e = tid; e < 8 * npx; e += 256) {
        int o = e & 7, n = e >> 3;
        int y = n / pn, x = n - y * pn;
        int sh = (y * HH) / pn, eh = ((y + 1) * HH + pn - 1) / pn;
        int sw = (x * HH) / pn, ew = ((x + 1) * HH + pn - 1) / pn;
        float s = 0.f;
        for (int yy = sh; yy < eh; ++yy)
            for (int xx = sw; xx < ew; ++xx) s += fh_s[o][yy * 16 + xx];
        out[((bb * 680) + off + n) * 32 + og + o] = s * (1.f / (float)((eh - sh) * (ew - sw)));
    }

    if (pn2 > 0) {
        int npx2 = pn2 * pn2;
        for (int e = tid; e < 8 * npx2; e += 256) {
            int o = e / npx2, n = e - o * npx2;
            int y = n / pn2, x = n - y * pn2;
            int sh = (y * HH) / pn2, eh = ((y + 1) * HH + pn2 - 1) / pn2;
            int sw = (x * HH) / pn2, ew = ((x + 1) * HH + pn2 - 1) / pn2;
            float s = 0.f;
            for (int yy = sh; yy < eh; ++yy)
                for (int xx = sw; xx < ew; ++xx) s += fr_s[o][yy * 16 + xx];
            znext[(bb * 32 + og + o) * npx2 + n] = s * (1.f / (float)((eh - sh) * (ew - sw)));
        }
    }
}

// ---------------- launch ----------------

extern "C" void kernel_launch(void* const* d_in, const int* in_sizes, int n_in,
                              void* d_out, int out_size, void* d_ws, size_t ws_size,
                              hipStream_t stream) {
    const float* feat = (const float*)d_in[0];
    const float* cb   = (const float*)d_in[1];
    const float* phiw = (const float*)d_in[2];
    const float* phib = (const float*)d_in[3];
    float* out = (float*)d_out;
    float* wsf = (float*)d_ws;

    const int NE = B * C * HH * HH; // 1048576
    float* f_rest = wsf;
    float* f_hat  = wsf + NE;
    float* zA     = wsf + 2 * NE;
    float* zB     = wsf + 3 * NE;
    char*  tl     = (char*)(wsf + 4 * NE);
    double* c2d  = (double*)tl;                             // 32 KB
    float*  c2f  = (float*)(tl + (32 << 10));               // 16 KB
    float*  pb1  = (float*)(tl + (48 << 10));               // 1 MB each
    float*  pb2  = (float*)(tl + (48 << 10) + (1 << 20));
    int*    pi1  = (int*)  (tl + (48 << 10) + (2 << 20));
    unsigned short* cbh = (unsigned short*)(tl + (48 << 10) + (3 << 20));        // 256 KB
    unsigned short* cbl = (unsigned short*)(tl + (48 << 10) + (3 << 20) + (512 << 10));

    static const int PN_[10]   = {1, 2, 3, 4, 5, 6, 8, 10, 13, 16};
    static const int PI_[10]   = {0, 0, 1, 1, 1, 2, 2, 2, 3, 3};
    static const int OFF_[10]  = {0, 1, 5, 14, 30, 55, 91, 155, 255, 424};
    static const int NSEG_[10] = {32, 32, 32, 16, 16, 16, 8, 8, 8, 8};

    setup_kernel<<<dim3((NE + 255) / 256), dim3(256), 0, stream>>>(
        feat, f_rest, f_hat, cb, c2d, c2f, zA, cbh, cbl);

    for (int si = 0; si < 10; ++si) {
        int pn = PN_[si], npx = pn * pn;
        int tokens = B * npx;
        int nseg = NSEG_[si];
        int ngrp = tokens / 32;
        int njobs = ngrp * nseg;         // divisible by 4 at every stage
        float* zin  = (si & 1) ? zB : zA;
        float* zout = (si & 1) ? zA : zB;

        scan_mfma_kernel<<<dim3(njobs / 4), dim3(256), 0, stream>>>(
            zin, cbh, cbl, c2f, pb1, pb2, pi1, npx, nseg, ngrp);

        int pn2 = (si < 9) ? PN_[si + 1] : 0;
        stage_tail_kernel<<<dim3(B * 4), dim3(256), 0, stream>>>(
            pb1, pb2, pi1, zin, cb, c2d,
            phiw + PI_[si] * C * C * 9, phib + PI_[si] * C,
            f_hat, f_rest, out, zout, pn, OFF_[si], pn2, nseg);
    }
}

// Round 20
// 835.187 us; speedup vs baseline: 1.0995x; 1.0440x over previous
//
#include <hip/hip_runtime.h>

#define B 128
#define C 32
#define HH 16
#define V 4096
#define MARGIN 1e-4f

typedef __attribute__((ext_vector_type(8))) short bf16x8;
typedef __attribute__((ext_vector_type(4))) float f32x4;

// ---------------- helpers ----------------

__device__ __forceinline__ float cubicw(float t) {
    float at = fabsf(t);
    float at2 = at * at, at3 = at2 * at;
    if (at <= 1.f) return 1.25f * at3 - 2.25f * at2 + 1.f;
    if (at < 2.f)  return -0.75f * at3 + 3.75f * at2 - 6.f * at + 3.f;
    return 0.f;
}

__device__ __forceinline__ unsigned short f2bf_rne(float f) {
    unsigned int u = __float_as_uint(f);
    unsigned int r = (u + 0x7fffu + ((u >> 16) & 1u)) >> 16;
    return (unsigned short)r;
}
__device__ __forceinline__ float bf2f(unsigned short h) {
    return __uint_as_float(((unsigned int)h) << 16);
}

// ---------------- kernels ----------------

// setup: f_rest=feat, f_hat=0, c2 (fp64+fp32), stage-0 z, codebook bf16 hi/lo frag tables
__global__ void setup_kernel(const float* __restrict__ feat, float* __restrict__ f_rest,
                             float* __restrict__ f_hat, const float* __restrict__ cb,
                             double* __restrict__ c2d, float* __restrict__ c2f,
                             float* __restrict__ z0, unsigned short* __restrict__ cbh,
                             unsigned short* __restrict__ cbl) {
    int i = blockIdx.x * 256 + threadIdx.x;
    if (i < B * C * HH * HH) { f_rest[i] = feat[i]; f_hat[i] = 0.f; }
    if (i < V) {
        const float* p = cb + i * C;
        double s = 0.0;
        #pragma unroll
        for (int j = 0; j < C; ++j) { double d = (double)p[j]; s = fma(d, d, s); }
        c2d[i] = s;
        c2f[i] = (float)s;
    }
    if (i < B * C) {
        const float* p = feat + i * (HH * HH);
        float s = 0.f;
        for (int px = 0; px < HH * HH; ++px) s += p[px];
        z0[i] = s * (1.f / 256.f);
    }
    if (i < V * C) {
        int ii = i & 7, nn = (i >> 3) & 15, kb = (i >> 7) & 3, T = i >> 9;
        float val = cb[(T * 16 + nn) * C + kb * 8 + ii];
        unsigned short h = f2bf_rne(val);
        cbh[i] = h;
        cbl[i] = f2bf_rne(val - bf2f(h));
    }
}

// ---- MFMA top-2 scan (R19 structure): output packed as 16B {b1,b2,idx,pad} ----
__global__ __launch_bounds__(256, 4) void scan_mfma_kernel(
    const float* __restrict__ z, const unsigned short* __restrict__ cbh,
    const unsigned short* __restrict__ cbl, const float* __restrict__ c2f,
    float4* __restrict__ pk, int npx, int nseg, int ngrp)
{
    int tid = threadIdx.x;
    int wave = tid >> 6, lane = tid & 63;
    int job = blockIdx.x * 4 + wave;
    int seg = job / ngrp, tokgrp = job - seg * ngrp;
    int cps = V / nseg;
    int total = B * npx;
    int tn = lane & 15, kb = lane >> 4;

    __shared__ alignas(16) char ldsu[26112];
    short* ldsA = (short*)ldsu;
    float* smb1 = (float*)ldsu;
    float* smb2 = (float*)(ldsu + 8704);
    int*   smi1 = (int*)(ldsu + 17408);

    {
        #pragma unroll
        for (int g = 0; g < 2; ++g) {
            int tok = tokgrp * 32 + g * 16 + tn;
            int bq = tok / npx, n = tok - bq * npx;
            short hi[8], lo[8];
            #pragma unroll
            for (int i = 0; i < 8; ++i) {
                float v = z[(bq * C + kb * 8 + i) * npx + n];
                unsigned short h = f2bf_rne(v);
                hi[i] = (short)h;
                lo[i] = (short)f2bf_rne(v - bf2f(h));
            }
            short* sh_ = ldsA + ((wave * 4 + g * 2) * 64 + lane) * 8;
            short* sl_ = ldsA + ((wave * 4 + g * 2 + 1) * 64 + lane) * 8;
            #pragma unroll
            for (int i = 0; i < 8; ++i) { sh_[i] = hi[i]; sl_[i] = lo[i]; }
        }
    }
    __syncthreads();

    const bf16x8* fp = reinterpret_cast<const bf16x8*>(ldsA);
    const bf16x8* ph = reinterpret_cast<const bf16x8*>(cbh);
    const bf16x8* pl = reinterpret_cast<const bf16x8*>(cbl);

    float b1[8], b2[8]; int i1[8];
    #pragma unroll
    for (int s = 0; s < 8; ++s) { b1[s] = 3e38f; b2[s] = 3e38f; i1[s] = 0; }

    int T0 = seg * (cps >> 4), nT = cps >> 4;
    bf16x8 bh = ph[(size_t)T0 * 64 + lane];
    bf16x8 bl = pl[(size_t)T0 * 64 + lane];
    float c2v = c2f[T0 * 16 + tn];

    #pragma unroll 1
    for (int t = 0; t < nT; ++t) {
        asm volatile("" ::: "memory");
        bf16x8 a0h = fp[(wave * 4 + 0) * 64 + lane];
        bf16x8 a0l = fp[(wave * 4 + 1) * 64 + lane];
        bf16x8 a1h = fp[(wave * 4 + 2) * 64 + lane];
        bf16x8 a1l = fp[(wave * 4 + 3) * 64 + lane];

        int Tn = T0 + ((t + 1 < nT) ? t + 1 : t);
        bf16x8 nbh = ph[(size_t)Tn * 64 + lane];
        bf16x8 nbl = pl[(size_t)Tn * 64 + lane];
        float nc2 = c2f[Tn * 16 + tn];

        f32x4 a0 = {0.f, 0.f, 0.f, 0.f}, a1 = {0.f, 0.f, 0.f, 0.f};
        a0 = __builtin_amdgcn_mfma_f32_16x16x32_bf16(a0h, bh, a0, 0, 0, 0);
        a0 = __builtin_amdgcn_mfma_f32_16x16x32_bf16(a0l, bh, a0, 0, 0, 0);
        a0 = __builtin_amdgcn_mfma_f32_16x16x32_bf16(a0h, bl, a0, 0, 0, 0);
        a0 = __builtin_amdgcn_mfma_f32_16x16x32_bf16(a0l, bl, a0, 0, 0, 0);
        a1 = __builtin_amdgcn_mfma_f32_16x16x32_bf16(a1h, bh, a1, 0, 0, 0);
        a1 = __builtin_amdgcn_mfma_f32_16x16x32_bf16(a1l, bh, a1, 0, 0, 0);
        a1 = __builtin_amdgcn_mfma_f32_16x16x32_bf16(a1h, bl, a1, 0, 0, 0);
        a1 = __builtin_amdgcn_mfma_f32_16x16x32_bf16(a1l, bl, a1, 0, 0, 0);

        int code = (T0 + t) * 16 + tn;
        #pragma unroll
        for (int r = 0; r < 4; ++r) {
            float s0 = fmaf(-2.f, a0[r], c2v);
            if (s0 < b1[r]) { b2[r] = b1[r]; b1[r] = s0; i1[r] = code; }
            else if (s0 < b2[r]) { b2[r] = s0; }
            float s1 = fmaf(-2.f, a1[r], c2v);
            if (s1 < b1[4 + r]) { b2[4 + r] = b1[4 + r]; b1[4 + r] = s1; i1[4 + r] = code; }
            else if (s1 < b2[4 + r]) { b2[4 + r] = s1; }
        }
        bh = nbh; bl = nbl; c2v = nc2;
    }

    __syncthreads();
    #pragma unroll
    for (int g = 0; g < 2; ++g)
        #pragma unroll
        for (int r = 0; r < 4; ++r) {
            int tokl = g * 16 + kb * 4 + r;
            int base = wave * 544 + tokl * 17 + tn;
            smb1[base] = b1[g * 4 + r];
            smb2[base] = b2[g * 4 + r];
            smi1[base] = i1[g * 4 + r];
        }
    __syncthreads();
    if (tid < 128) {
        int w = tid >> 5, tl = tid & 31;
        int jobw = blockIdx.x * 4 + w;
        int segw = jobw / ngrp, tgw = jobw - segw * ngrp;
        float gb1 = 3e38f, gb2 = 3e38f; int gi1 = 0;
        #pragma unroll
        for (int i = 0; i < 16; ++i) {
            float v1 = smb1[w * 544 + tl * 17 + i];
            int   ix = smi1[w * 544 + tl * 17 + i];
            if (v1 < gb1 || (v1 == gb1 && ix < gi1)) { gb2 = gb1; gb1 = v1; gi1 = ix; }
            else if (v1 < gb2) { gb2 = v1; }
            float v2 = smb2[w * 544 + tl * 17 + i];
            if (v2 < gb2) gb2 = v2;
        }
        int tok = tgw * 32 + tl;
        float4 o;
        o.x = gb1; o.y = gb2; o.z = __int_as_float(gi1); o.w = 0.f;
        pk[(size_t)segw * total + tok] = o;
    }
}

// fused tail v4: w staged in LDS early (hides under combine); packed 16B combine
// loads; 16-channel bicubic chunks (4 barriers).  B*4 blocks, 8 out-ch each.
__global__ __launch_bounds__(256) void stage_tail_kernel(
    const float4* __restrict__ pk, const float* __restrict__ z,
    const float* __restrict__ cb, const double* __restrict__ c2d,
    const float* __restrict__ w, const float* __restrict__ bias,
    float* __restrict__ f_hat, float* __restrict__ f_rest,
    float* __restrict__ out, float* __restrict__ znext,
    int pn, int off, int pn2, int nseg)
{
    int bb = blockIdx.x >> 2;
    int og = (blockIdx.x & 3) * 8;
    int tid = threadIdx.x;
    int npx = pn * pn;
    int total = B * npx;

    __shared__ float A_s[32][257];      // gather -> hu -> fh/fr overlay (rows 0..15)
    __shared__ float Bc[16][257];       // bicubic v-pass temp, 16-ch chunks
    __shared__ alignas(16) float w_s[8 * 384];   // [o][i][12] padded, 12.3 KB
    __shared__ int idx_s[256];
    __shared__ int flist[256];
    __shared__ int fcnt;
    __shared__ double zsd[C];
    __shared__ double sred[256];
    __shared__ int sidx[256];
    __shared__ float wtab[16][4];
    __shared__ int   itab[16][4];
    float (*fh_s)[257] = &A_s[0];
    float (*fr_s)[257] = &A_s[8];

    // prefetch f_hat/f_rest + stage weights EARLY (latency hides under combine/recheck)
    float pf[8], pr[8];
    #pragma unroll
    for (int o = 0; o < 8; ++o) {
        int gi = (bb * 32 + og + o) * 256 + tid;
        pf[o] = f_hat[gi]; pr[o] = f_rest[gi];
    }
    for (int e = tid; e < 8 * 288; e += 256) {
        int o = e / 288, r = e - o * 288;
        w_s[o * 384 + (r / 9) * 12 + (r % 9)] = w[(size_t)og * 288 + e];
    }

    if (tid < 16) {
        float scale = (float)pn * (1.f / 16.f);
        float src = (tid + 0.5f) * scale - 0.5f;
        int fi = (int)floorf(src);
        float t = src - (float)fi;
        #pragma unroll
        for (int k = 0; k < 4; ++k) {
            wtab[tid][k] = cubicw((float)(k - 1) - t);
            itab[tid][k] = min(max(fi + k - 1, 0), pn - 1);
        }
    }
    if (tid == 0) fcnt = 0;
    __syncthreads();

    // combine per-segment top-2 (one 16B load per segment)
    if (tid < npx) {
        int tok = bb * npx + tid;
        float gb1 = 3e38f, gb2 = 3e38f; int gi1 = 0;
        for (int s = 0; s < nseg; ++s) {
            float4 e = pk[(size_t)s * total + tok];
            float v1 = e.x; int ix = __float_as_int(e.z);
            if (v1 < gb1 || (v1 == gb1 && ix < gi1)) { gb2 = gb1; gb1 = v1; gi1 = ix; }
            else if (v1 < gb2) { gb2 = v1; }
            if (e.y < gb2) gb2 = e.y;
        }
        idx_s[tid] = gi1;
        if (gb2 - gb1 < MARGIN) { int slot = atomicAdd(&fcnt, 1); flist[slot] = tid; }
    }
    __syncthreads();

    // exact fp64 rescan for ambiguous tokens
    int nf = fcnt;
    for (int f = 0; f < nf; ++f) {
        int n = flist[f];
        if (tid < C) zsd[tid] = (double)z[(bb * C + tid) * npx + n];
        __syncthreads();
        double best = 1e300; int bi = 0x7fffffff;
        for (int k = 0; k < V / 256; ++k) {
            int v = tid + k * 256;
            const float4* cp = reinterpret_cast<const float4*>(cb + (size_t)v * C);
            double acc = 0.0;
            #pragma unroll
            for (int qq = 0; qq < 8; ++qq) {
                float4 fv = cp[qq];
                acc = fma((double)fv.x, zsd[4 * qq + 0], acc);
                acc = fma((double)fv.y, zsd[4 * qq + 1], acc);
                acc = fma((double)fv.z, zsd[4 * qq + 2], acc);
                acc = fma((double)fv.w, zsd[4 * qq + 3], acc);
            }
            double s = fma(-2.0, acc, c2d[v]);
            if (s < best || (s == best && v < bi)) { best = s; bi = v; }
        }
        sred[tid] = best; sidx[tid] = bi;
        __syncthreads();
        for (int st = 128; st > 0; st >>= 1) {
            if (tid < st) {
                double o = sred[tid + st]; int oi = sidx[tid + st];
                double me = sred[tid];     int mi = sidx[tid];
                if (o < me || (o == me && oi < mi)) { sred[tid] = o; sidx[tid] = oi; }
            }
            __syncthreads();
        }
        if (tid == 0) idx_s[n] = sidx[0];
        __syncthreads();
    }
    __syncthreads();

    // gather
    for (int e = tid; e < 32 * npx; e += 256) {
        int c = e & 31, n = e >> 5;
        A_s[c][n] = cb[idx_s[n] * 32 + c];
    }
    __syncthreads();

    // separable bicubic in 2 chunks of 16 channels
    #pragma unroll 1
    for (int ch = 0; ch < 2; ++ch) {
        for (int e = tid; e < 16 * 16 * pn; e += 256) {
            int wx = e % pn; int rest = e / pn;
            int p = rest & 15, cl = rest >> 4;
            float s = 0.f;
            #pragma unroll
            for (int k = 0; k < 4; ++k)
                s = fmaf(wtab[p][k], A_s[ch * 16 + cl][itab[p][k] * pn + wx], s);
            Bc[cl][p * pn + wx] = s;
        }
        __syncthreads();
        #pragma unroll
        for (int it = 0; it < 16; ++it) {
            int e = tid + it * 256;
            int q = e & 15, p = (e >> 4) & 15, cl = e >> 8;
            float s = 0.f;
            #pragma unroll
            for (int k = 0; k < 4; ++k)
                s = fmaf(wtab[q][k], Bc[cl][p * pn + itab[q][k]], s);
            A_s[ch * 16 + cl][e & 255] = s;
        }
        __syncthreads();
    }

    // conv 3x3 SAME over 32 in-ch (A_s = hu) for out-ch og..og+7; w via LDS broadcast
    int p = tid >> 4, q = tid & 15;
    float acc[8];
    #pragma unroll
    for (int o = 0; o < 8; ++o) acc[o] = bias[og + o];
    for (int i = 0; i < 32; ++i) {
        float v[9];
        #pragma unroll
        for (int dy = 0; dy < 3; ++dy)
            #pragma unroll
            for (int dx = 0; dx < 3; ++dx) {
                int pp = p + dy - 1, qq = q + dx - 1;
                bool in = (pp >= 0) & (pp < 16) & (qq >= 0) & (qq < 16);
                v[dy * 3 + dx] = in ? A_s[i][pp * 16 + qq] : 0.f;
            }
        #pragma unroll
        for (int o = 0; o < 8; ++o) {
            const float* wr = &w_s[o * 384 + i * 12];
            float4 wa = *reinterpret_cast<const float4*>(wr);
            float4 wb = *reinterpret_cast<const float4*>(wr + 4);
            float w8 = wr[8];
            acc[o] = fmaf(wa.x, v[0], acc[o]); acc[o] = fmaf(wa.y, v[1], acc[o]);
            acc[o] = fmaf(wa.z, v[2], acc[o]); acc[o] = fmaf(wa.w, v[3], acc[o]);
            acc[o] = fmaf(wb.x, v[4], acc[o]); acc[o] = fmaf(wb.y, v[5], acc[o]);
            acc[o] = fmaf(wb.z, v[6], acc[o]); acc[o] = fmaf(wb.w, v[7], acc[o]);
            acc[o] = fmaf(w8,   v[8], acc[o]);
        }
    }
    float hv[8];
    #pragma unroll
    for (int o = 0; o < 8; ++o) hv[o] = A_s[og + o][tid];
    __syncthreads();   // all A_s reads done before overlay writes

    #pragma unroll
    for (int o = 0; o < 8; ++o) {
        int gi = (bb * 32 + og + o) * 256 + tid;
        float blend = 0.5f * hv[o] + 0.5f * acc[o];
        float nf2 = pf[o] + blend;
        float nr2 = pr[o] - blend;
        f_hat[gi] = nf2; f_rest[gi] = nr2;
        fh_s[o][tid] = nf2; fr_s[o][tid] = nr2;
    }
    __syncthreads();

    for (int e = tid; e < 8 * npx; e += 256) {
        int o = e & 7, n = e >> 3;
        int y = n / pn, x = n - y * pn;
        int sh = (y * HH) / pn, eh = ((y + 1) * HH + pn - 1) / pn;
        int sw = (x * HH) / pn, ew = ((x + 1) * HH + pn - 1) / pn;
        float s = 0.f;
        for (int yy = sh; yy < eh; ++yy)
            for (int xx = sw; xx < ew; ++xx) s += fh_s[o][yy * 16 + xx];
        out[((bb * 680) + off + n) * 32 + og + o] = s * (1.f / (float)((eh - sh) * (ew - sw)));
    }

    if (pn2 > 0) {
        int npx2 = pn2 * pn2;
        for (int e = tid; e < 8 * npx2; e += 256) {
            int o = e / npx2, n = e - o * npx2;
            int y = n / pn2, x = n - y * pn2;
            int sh = (y * HH) / pn2, eh = ((y + 1) * HH + pn2 - 1) / pn2;
            int sw = (x * HH) / pn2, ew = ((x + 1) * HH + pn2 - 1) / pn2;
            float s = 0.f;
            for (int yy = sh; yy < eh; ++yy)
                for (int xx = sw; xx < ew; ++xx) s += fr_s[o][yy * 16 + xx];
            znext[(bb * 32 + og + o) * npx2 + n] = s * (1.f / (float)((eh - sh) * (ew - sw)));
        }
    }
}

// ---------------- launch ----------------

extern "C" void kernel_launch(void* const* d_in, const int* in_sizes, int n_in,
                              void* d_out, int out_size, void* d_ws, size_t ws_size,
                              hipStream_t stream) {
    const float* feat = (const float*)d_in[0];
    const float* cb   = (const float*)d_in[1];
    const float* phiw = (const float*)d_in[2];
    const float* phib = (const float*)d_in[3];
    float* out = (float*)d_out;
    float* wsf = (float*)d_ws;

    const int NE = B * C * HH * HH; // 1048576
    float* f_rest = wsf;
    float* f_hat  = wsf + NE;
    float* zA     = wsf + 2 * NE;
    float* zB     = wsf + 3 * NE;
    char*  tl     = (char*)(wsf + 4 * NE);
    double* c2d  = (double*)tl;                             // 32 KB
    float*  c2f  = (float*)(tl + (32 << 10));               // 16 KB
    float4* pk   = (float4*)(tl + (48 << 10));              // 4 MB (8 seg x 32768 x 16B max)
    unsigned short* cbh = (unsigned short*)(tl + (48 << 10) + (4 << 20));   // 256 KB
    unsigned short* cbl = (unsigned short*)(tl + (48 << 10) + (4 << 20) + (512 << 10));

    static const int PN_[10]   = {1, 2, 3, 4, 5, 6, 8, 10, 13, 16};
    static const int PI_[10]   = {0, 0, 1, 1, 1, 2, 2, 2, 3, 3};
    static const int OFF_[10]  = {0, 1, 5, 14, 30, 55, 91, 155, 255, 424};
    static const int NSEG_[10] = {32, 32, 32, 16, 16, 16, 8, 8, 8, 8};

    setup_kernel<<<dim3((NE + 255) / 256), dim3(256), 0, stream>>>(
        feat, f_rest, f_hat, cb, c2d, c2f, zA, cbh, cbl);

    for (int si = 0; si < 10; ++si) {
        int pn = PN_[si], npx = pn * pn;
        int tokens = B * npx;
        int nseg = NSEG_[si];
        int ngrp = tokens / 32;
        int njobs = ngrp * nseg;         // divisible by 4 at every stage
        float* zin  = (si & 1) ? zB : zA;
        float* zout = (si & 1) ? zA : zB;

        scan_mfma_kernel<<<dim3(njobs / 4), dim3(256), 0, stream>>>(
            zin, cbh, cbl, c2f, pk, npx, nseg, ngrp);

        int pn2 = (si < 9) ? PN_[si + 1] : 0;
        stage_tail_kernel<<<dim3(B * 4), dim3(256), 0, stream>>>(
            pk, zin, cb, c2d,
            phiw + PI_[si] * C * C * 9, phib + PI_[si] * C,
            f_hat, f_rest, out, zout, pn, OFF_[si], pn2, nseg);
    }
}

// Round 21
// 687.630 us; speedup vs baseline: 1.3354x; 1.2146x over previous
//
#include <hip/hip_runtime.h>

#define B 128
#define C 32
#define HH 16
#define V 4096
#define MARGIN 1e-4f

typedef __attribute__((ext_vector_type(8))) short bf16x8;
typedef __attribute__((ext_vector_type(4))) float f32x4;

// ---------------- helpers ----------------

__device__ __forceinline__ float cubicw(float t) {
    float at = fabsf(t);
    float at2 = at * at, at3 = at2 * at;
    if (at <= 1.f) return 1.25f * at3 - 2.25f * at2 + 1.f;
    if (at < 2.f)  return -0.75f * at3 + 3.75f * at2 - 6.f * at + 3.f;
    return 0.f;
}

__device__ __forceinline__ unsigned short f2bf_rne(float f) {
    unsigned int u = __float_as_uint(f);
    unsigned int r = (u + 0x7fffu + ((u >> 16) & 1u)) >> 16;
    return (unsigned short)r;
}
__device__ __forceinline__ float bf2f(unsigned short h) {
    return __uint_as_float(((unsigned int)h) << 16);
}

// ---------------- kernels ----------------

// setup: f_rest=feat, f_hat=0, c2 (fp64+fp32), stage-0 z, codebook bf16 hi/lo frag tables
__global__ void setup_kernel(const float* __restrict__ feat, float* __restrict__ f_rest,
                             float* __restrict__ f_hat, const float* __restrict__ cb,
                             double* __restrict__ c2d, float* __restrict__ c2f,
                             float* __restrict__ z0, unsigned short* __restrict__ cbh,
                             unsigned short* __restrict__ cbl) {
    int i = blockIdx.x * 256 + threadIdx.x;
    if (i < B * C * HH * HH) { f_rest[i] = feat[i]; f_hat[i] = 0.f; }
    if (i < V) {
        const float* p = cb + i * C;
        double s = 0.0;
        #pragma unroll
        for (int j = 0; j < C; ++j) { double d = (double)p[j]; s = fma(d, d, s); }
        c2d[i] = s;
        c2f[i] = (float)s;
    }
    if (i < B * C) {
        const float* p = feat + i * (HH * HH);
        float s = 0.f;
        for (int px = 0; px < HH * HH; ++px) s += p[px];
        z0[i] = s * (1.f / 256.f);
    }
    if (i < V * C) {
        int ii = i & 7, nn = (i >> 3) & 15, kb = (i >> 7) & 3, T = i >> 9;
        float val = cb[(T * 16 + nn) * C + kb * 8 + ii];
        unsigned short h = f2bf_rne(val);
        cbh[i] = h;
        cbl[i] = f2bf_rne(val - bf2f(h));
    }
}

// ---- MFMA top-2 scan v5: 16 tokens/wave -> per-thread state ~40 VGPR, fits the
// compiler's ~44-reg envelope. R16-R20 failure mode: 32-token state (56+) forced
// top-2 into L2-resident scratch (invisible to HBM counters), ~2x slowdown. ----
__global__ __launch_bounds__(256) void scan_mfma_kernel(
    const float* __restrict__ z, const unsigned short* __restrict__ cbh,
    const unsigned short* __restrict__ cbl, const float* __restrict__ c2f,
    float4* __restrict__ pk, int npx, int nseg, int ngrp)
{
    int tid = threadIdx.x;
    int wave = tid >> 6, lane = tid & 63;
    int job = blockIdx.x * 4 + wave;
    int seg = job / ngrp, tokgrp = job - seg * ngrp;
    int cps = V / nseg;
    int total = B * npx;
    int tn = lane & 15, kb = lane >> 4;

    __shared__ float smb1[4][16 * 17];
    __shared__ float smb2[4][16 * 17];
    __shared__ int   smi1[4][16 * 17];

    // build this lane's A-fragment pair in registers (8 VGPR total)
    bf16x8 ah, al;
    {
        int tok = tokgrp * 16 + tn;
        int bq = tok / npx, n = tok - bq * npx;
        #pragma unroll
        for (int i = 0; i < 8; ++i) {
            float v = z[(bq * C + kb * 8 + i) * npx + n];
            unsigned short h = f2bf_rne(v);
            ah[i] = (short)h;
            al[i] = (short)f2bf_rne(v - bf2f(h));
        }
    }

    const bf16x8* ph = reinterpret_cast<const bf16x8*>(cbh);
    const bf16x8* pl = reinterpret_cast<const bf16x8*>(cbl);

    float b1[4], b2[4]; int i1[4];
    #pragma unroll
    for (int s = 0; s < 4; ++s) { b1[s] = 3e38f; b2[s] = 3e38f; i1[s] = 0; }

    int T0 = seg * (cps >> 4), nT = cps >> 4;
    #pragma unroll 1
    for (int t = 0; t < nT; ++t) {
        int T = T0 + t;
        bf16x8 bh = ph[(size_t)T * 64 + lane];
        bf16x8 bl = pl[(size_t)T * 64 + lane];
        float c2v = c2f[T * 16 + tn];

        f32x4 a0 = {0.f, 0.f, 0.f, 0.f};
        a0 = __builtin_amdgcn_mfma_f32_16x16x32_bf16(ah, bh, a0, 0, 0, 0);
        a0 = __builtin_amdgcn_mfma_f32_16x16x32_bf16(al, bh, a0, 0, 0, 0);
        a0 = __builtin_amdgcn_mfma_f32_16x16x32_bf16(ah, bl, a0, 0, 0, 0);
        a0 = __builtin_amdgcn_mfma_f32_16x16x32_bf16(al, bl, a0, 0, 0, 0);

        int code = T * 16 + tn;   // ascending with t -> strict < keeps lowest idx
        #pragma unroll
        for (int r = 0; r < 4; ++r) {
            float s0 = fmaf(-2.f, a0[r], c2v);
            if (s0 < b1[r]) { b2[r] = b1[r]; b1[r] = s0; i1[r] = code; }
            else if (s0 < b2[r]) { b2[r] = s0; }
        }
    }

    // lane holds top-2 (over codes === tn mod 16) for tokens kb*4+r
    #pragma unroll
    for (int r = 0; r < 4; ++r) {
        int tokl = kb * 4 + r;
        smb1[wave][tokl * 17 + tn] = b1[r];
        smb2[wave][tokl * 17 + tn] = b2[r];
        smi1[wave][tokl * 17 + tn] = i1[r];
    }
    __syncthreads();
    if (tid < 64) {
        int w = tid >> 4, tl = tid & 15;
        int jobw = blockIdx.x * 4 + w;
        int segw = jobw / ngrp, tgw = jobw - segw * ngrp;
        float gb1 = 3e38f, gb2 = 3e38f; int gi1 = 0;
        #pragma unroll
        for (int i = 0; i < 16; ++i) {
            float v1 = smb1[w][tl * 17 + i];
            int   ix = smi1[w][tl * 17 + i];
            if (v1 < gb1 || (v1 == gb1 && ix < gi1)) { gb2 = gb1; gb1 = v1; gi1 = ix; }
            else if (v1 < gb2) { gb2 = v1; }
            float v2 = smb2[w][tl * 17 + i];
            if (v2 < gb2) gb2 = v2;
        }
        int tok = tgw * 16 + tl;
        float4 o;
        o.x = gb1; o.y = gb2; o.z = __int_as_float(gi1); o.w = 0.f;
        pk[(size_t)segw * total + tok] = o;
    }
}

// fused tail v4 (R20, unchanged): w staged in LDS early; packed 16B combine loads;
// 16-channel bicubic chunks.  B*4 blocks, 8 out-ch each.
__global__ __launch_bounds__(256) void stage_tail_kernel(
    const float4* __restrict__ pk, const float* __restrict__ z,
    const float* __restrict__ cb, const double* __restrict__ c2d,
    const float* __restrict__ w, const float* __restrict__ bias,
    float* __restrict__ f_hat, float* __restrict__ f_rest,
    float* __restrict__ out, float* __restrict__ znext,
    int pn, int off, int pn2, int nseg)
{
    int bb = blockIdx.x >> 2;
    int og = (blockIdx.x & 3) * 8;
    int tid = threadIdx.x;
    int npx = pn * pn;
    int total = B * npx;

    __shared__ float A_s[32][257];
    __shared__ float Bc[16][257];
    __shared__ alignas(16) float w_s[8 * 384];
    __shared__ int idx_s[256];
    __shared__ int flist[256];
    __shared__ int fcnt;
    __shared__ double zsd[C];
    __shared__ double sred[256];
    __shared__ int sidx[256];
    __shared__ float wtab[16][4];
    __shared__ int   itab[16][4];
    float (*fh_s)[257] = &A_s[0];
    float (*fr_s)[257] = &A_s[8];

    float pf[8], pr[8];
    #pragma unroll
    for (int o = 0; o < 8; ++o) {
        int gi = (bb * 32 + og + o) * 256 + tid;
        pf[o] = f_hat[gi]; pr[o] = f_rest[gi];
    }
    for (int e = tid; e < 8 * 288; e += 256) {
        int o = e / 288, r = e - o * 288;
        w_s[o * 384 + (r / 9) * 12 + (r % 9)] = w[(size_t)og * 288 + e];
    }

    if (tid < 16) {
        float scale = (float)pn * (1.f / 16.f);
        float src = (tid + 0.5f) * scale - 0.5f;
        int fi = (int)floorf(src);
        float t = src - (float)fi;
        #pragma unroll
        for (int k = 0; k < 4; ++k) {
            wtab[tid][k] = cubicw((float)(k - 1) - t);
            itab[tid][k] = min(max(fi + k - 1, 0), pn - 1);
        }
    }
    if (tid == 0) fcnt = 0;
    __syncthreads();

    if (tid < npx) {
        int tok = bb * npx + tid;
        float gb1 = 3e38f, gb2 = 3e38f; int gi1 = 0;
        for (int s = 0; s < nseg; ++s) {
            float4 e = pk[(size_t)s * total + tok];
            float v1 = e.x; int ix = __float_as_int(e.z);
            if (v1 < gb1 || (v1 == gb1 && ix < gi1)) { gb2 = gb1; gb1 = v1; gi1 = ix; }
            else if (v1 < gb2) { gb2 = v1; }
            if (e.y < gb2) gb2 = e.y;
        }
        idx_s[tid] = gi1;
        if (gb2 - gb1 < MARGIN) { int slot = atomicAdd(&fcnt, 1); flist[slot] = tid; }
    }
    __syncthreads();

    int nf = fcnt;
    for (int f = 0; f < nf; ++f) {
        int n = flist[f];
        if (tid < C) zsd[tid] = (double)z[(bb * C + tid) * npx + n];
        __syncthreads();
        double best = 1e300; int bi = 0x7fffffff;
        for (int k = 0; k < V / 256; ++k) {
            int v = tid + k * 256;
            const float4* cp = reinterpret_cast<const float4*>(cb + (size_t)v * C);
            double acc = 0.0;
            #pragma unroll
            for (int qq = 0; qq < 8; ++qq) {
                float4 fv = cp[qq];
                acc = fma((double)fv.x, zsd[4 * qq + 0], acc);
                acc = fma((double)fv.y, zsd[4 * qq + 1], acc);
                acc = fma((double)fv.z, zsd[4 * qq + 2], acc);
                acc = fma((double)fv.w, zsd[4 * qq + 3], acc);
            }
            double s = fma(-2.0, acc, c2d[v]);
            if (s < best || (s == best && v < bi)) { best = s; bi = v; }
        }
        sred[tid] = best; sidx[tid] = bi;
        __syncthreads();
        for (int st = 128; st > 0; st >>= 1) {
            if (tid < st) {
                double o = sred[tid + st]; int oi = sidx[tid + st];
                double me = sred[tid];     int mi = sidx[tid];
                if (o < me || (o == me && oi < mi)) { sred[tid] = o; sidx[tid] = oi; }
            }
            __syncthreads();
        }
        if (tid == 0) idx_s[n] = sidx[0];
        __syncthreads();
    }
    __syncthreads();

    for (int e = tid; e < 32 * npx; e += 256) {
        int c = e & 31, n = e >> 5;
        A_s[c][n] = cb[idx_s[n] * 32 + c];
    }
    __syncthreads();

    #pragma unroll 1
    for (int ch = 0; ch < 2; ++ch) {
        for (int e = tid; e < 16 * 16 * pn; e += 256) {
            int wx = e % pn; int rest = e / pn;
            int p = rest & 15, cl = rest >> 4;
            float s = 0.f;
            #pragma unroll
            for (int k = 0; k < 4; ++k)
                s = fmaf(wtab[p][k], A_s[ch * 16 + cl][itab[p][k] * pn + wx], s);
            Bc[cl][p * pn + wx] = s;
        }
        __syncthreads();
        #pragma unroll
        for (int it = 0; it < 16; ++it) {
            int e = tid + it * 256;
            int q = e & 15, p = (e >> 4) & 15, cl = e >> 8;
            float s = 0.f;
            #pragma unroll
            for (int k = 0; k < 4; ++k)
                s = fmaf(wtab[q][k], Bc[cl][p * pn + itab[q][k]], s);
            A_s[ch * 16 + cl][e & 255] = s;
        }
        __syncthreads();
    }

    int p = tid >> 4, q = tid & 15;
    float acc[8];
    #pragma unroll
    for (int o = 0; o < 8; ++o) acc[o] = bias[og + o];
    for (int i = 0; i < 32; ++i) {
        float v[9];
        #pragma unroll
        for (int dy = 0; dy < 3; ++dy)
            #pragma unroll
            for (int dx = 0; dx < 3; ++dx) {
                int pp = p + dy - 1, qq = q + dx - 1;
                bool in = (pp >= 0) & (pp < 16) & (qq >= 0) & (qq < 16);
                v[dy * 3 + dx] = in ? A_s[i][pp * 16 + qq] : 0.f;
            }
        #pragma unroll
        for (int o = 0; o < 8; ++o) {
            const float* wr = &w_s[o * 384 + i * 12];
            float4 wa = *reinterpret_cast<const float4*>(wr);
            float4 wb = *reinterpret_cast<const float4*>(wr + 4);
            float w8 = wr[8];
            acc[o] = fmaf(wa.x, v[0], acc[o]); acc[o] = fmaf(wa.y, v[1], acc[o]);
            acc[o] = fmaf(wa.z, v[2], acc[o]); acc[o] = fmaf(wa.w, v[3], acc[o]);
            acc[o] = fmaf(wb.x, v[4], acc[o]); acc[o] = fmaf(wb.y, v[5], acc[o]);
            acc[o] = fmaf(wb.z, v[6], acc[o]); acc[o] = fmaf(wb.w, v[7], acc[o]);
            acc[o] = fmaf(w8,   v[8], acc[o]);
        }
    }
    float hv[8];
    #pragma unroll
    for (int o = 0; o < 8; ++o) hv[o] = A_s[og + o][tid];
    __syncthreads();

    #pragma unroll
    for (int o = 0; o < 8; ++o) {
        int gi = (bb * 32 + og + o) * 256 + tid;
        float blend = 0.5f * hv[o] + 0.5f * acc[o];
        float nf2 = pf[o] + blend;
        float nr2 = pr[o] - blend;
        f_hat[gi] = nf2; f_rest[gi] = nr2;
        fh_s[o][tid] = nf2; fr_s[o][tid] = nr2;
    }
    __syncthreads();

    for (int e = tid; e < 8 * npx; e += 256) {
        int o = e & 7, n = e >> 3;
        int y = n / pn, x = n - y * pn;
        int sh = (y * HH) / pn, eh = ((y + 1) * HH + pn - 1) / pn;
        int sw = (x * HH) / pn, ew = ((x + 1) * HH + pn - 1) / pn;
        float s = 0.f;
        for (int yy = sh; yy < eh; ++yy)
            for (int xx = sw; xx < ew; ++xx) s += fh_s[o][yy * 16 + xx];
        out[((bb * 680) + off + n) * 32 + og + o] = s * (1.f / (float)((eh - sh) * (ew - sw)));
    }

    if (pn2 > 0) {
        int npx2 = pn2 * pn2;
        for (int e = tid; e < 8 * npx2; e += 256) {
            int o = e / npx2, n = e - o * npx2;
            int y = n / pn2, x = n - y * pn2;
            int sh = (y * HH) / pn2, eh = ((y + 1) * HH + pn2 - 1) / pn2;
            int sw = (x * HH) / pn2, ew = ((x + 1) * HH + pn2 - 1) / pn2;
            float s = 0.f;
            for (int yy = sh; yy < eh; ++yy)
                for (int xx = sw; xx < ew; ++xx) s += fr_s[o][yy * 16 + xx];
            znext[(bb * 32 + og + o) * npx2 + n] = s * (1.f / (float)((eh - sh) * (ew - sw)));
        }
    }
}

// ---------------- launch ----------------

extern "C" void kernel_launch(void* const* d_in, const int* in_sizes, int n_in,
                              void* d_out, int out_size, void* d_ws, size_t ws_size,
                              hipStream_t stream) {
    const float* feat = (const float*)d_in[0];
    const float* cb   = (const float*)d_in[1];
    const float* phiw = (const float*)d_in[2];
    const float* phib = (const float*)d_in[3];
    float* out = (float*)d_out;
    float* wsf = (float*)d_ws;

    const int NE = B * C * HH * HH; // 1048576
    float* f_rest = wsf;
    float* f_hat  = wsf + NE;
    float* zA     = wsf + 2 * NE;
    float* zB     = wsf + 3 * NE;
    char*  tl     = (char*)(wsf + 4 * NE);
    double* c2d  = (double*)tl;                             // 32 KB
    float*  c2f  = (float*)(tl + (32 << 10));               // 16 KB
    float4* pk   = (float4*)(tl + (48 << 10));              // 4 MB
    unsigned short* cbh = (unsigned short*)(tl + (48 << 10) + (4 << 20));   // 256 KB
    unsigned short* cbl = (unsigned short*)(tl + (48 << 10) + (4 << 20) + (512 << 10));

    static const int PN_[10]   = {1, 2, 3, 4, 5, 6, 8, 10, 13, 16};
    static const int PI_[10]   = {0, 0, 1, 1, 1, 2, 2, 2, 3, 3};
    static const int OFF_[10]  = {0, 1, 5, 14, 30, 55, 91, 155, 255, 424};
    static const int NSEG_[10] = {32, 32, 32, 16, 16, 16, 8, 8, 8, 8};

    setup_kernel<<<dim3((NE + 255) / 256), dim3(256), 0, stream>>>(
        feat, f_rest, f_hat, cb, c2d, c2f, zA, cbh, cbl);

    for (int si = 0; si < 10; ++si) {
        int pn = PN_[si], npx = pn * pn;
        int tokens = B * npx;
        int nseg = NSEG_[si];
        int ngrp = tokens / 16;          // 16 tokens per wave now
        int njobs = ngrp * nseg;         // divisible by 4 at every stage
        float* zin  = (si & 1) ? zB : zA;
        float* zout = (si & 1) ? zA : zB;

        scan_mfma_kernel<<<dim3(njobs / 4), dim3(256), 0, stream>>>(
            zin, cbh, cbl, c2f, pk, npx, nseg, ngrp);

        int pn2 = (si < 9) ? PN_[si + 1] : 0;
        stage_tail_kernel<<<dim3(B * 4), dim3(256), 0, stream>>>(
            pk, zin, cb, c2d,
            phiw + PI_[si] * C * C * 9, phib + PI_[si] * C,
            f_hat, f_rest, out, zout, pn, OFF_[si], pn2, nseg);
    }
}